// Round 2
// baseline (904.671 us; speedup 1.0000x reference)
//
#include <hip/hip_runtime.h>
#include <hip/hip_bf16.h>

typedef __attribute__((ext_vector_type(8))) short bf16x8;
typedef __attribute__((ext_vector_type(8))) unsigned short u16x8;
typedef __attribute__((ext_vector_type(4))) float f32x4;

#define LOG2E 1.4426950408889634f

__device__ __forceinline__ float bf2f(unsigned short u) {
  union { unsigned int i; float f; } v; v.i = ((unsigned int)u) << 16; return v.f;
}
__device__ __forceinline__ unsigned short f2bf(float f) {
  union { float f; unsigned int i; } v; v.f = f;
  unsigned int r = v.i + 0x7FFFu + ((v.i >> 16) & 1u);  // RNE
  return (unsigned short)(r >> 16);
}

// ---------------- f32 -> bf16 straight cast (n multiple of 2048) ----------------
__global__ void cvt_bf16_k(const float* __restrict__ in, unsigned short* __restrict__ out,
                           long n) {
  long i = ((long)blockIdx.x * 256 + threadIdx.x) * 8;
  if (i + 8 > n) return;
  float4 a = *(const float4*)(in + i);
  float4 b = *(const float4*)(in + i + 4);
  u16x8 o;
  o[0] = f2bf(a.x); o[1] = f2bf(a.y); o[2] = f2bf(a.z); o[3] = f2bf(a.w);
  o[4] = f2bf(b.x); o[5] = f2bf(b.y); o[6] = f2bf(b.z); o[7] = f2bf(b.w);
  *(u16x8*)(out + i) = o;
}

// ---------------- f32 in -> bf16 out, transposed: out[c][r] = bf16(in[r][c]) ----------------
__global__ void cvt_transpose_k(const float* __restrict__ in, unsigned short* __restrict__ out,
                                long in_rs, long out_rs) {
  __shared__ unsigned short tile[32][33];
  int c0 = blockIdx.x * 32, r0 = blockIdx.y * 32;
  int tx = threadIdx.x & 31, ty = threadIdx.x >> 5;
#pragma unroll
  for (int i = 0; i < 32; i += 8)
    tile[ty + i][tx] = f2bf(in[(long)(r0 + ty + i) * in_rs + c0 + tx]);
  __syncthreads();
#pragma unroll
  for (int i = 0; i < 32; i += 8)
    out[(long)(c0 + ty + i) * out_rs + r0 + tx] = tile[tx][ty + i];
}

// ---------------- bf16 transpose: out[c][r] = in[r][c] ----------------
__global__ void transpose_k(const unsigned short* __restrict__ in,
                            unsigned short* __restrict__ out,
                            long in_rs, long out_rs, long in_zoff, long out_zoff) {
  __shared__ unsigned short tile[32][33];
  const unsigned short* ip = in + (long)blockIdx.z * in_zoff;
  unsigned short* op = out + (long)blockIdx.z * out_zoff;
  int c0 = blockIdx.x * 32, r0 = blockIdx.y * 32;
  int tx = threadIdx.x & 31, ty = threadIdx.x >> 5;
#pragma unroll
  for (int i = 0; i < 32; i += 8)
    tile[ty + i][tx] = ip[(long)(r0 + ty + i) * in_rs + c0 + tx];
  __syncthreads();
#pragma unroll
  for (int i = 0; i < 32; i += 8)
    op[(long)(c0 + ty + i) * out_rs + r0 + tx] = tile[tx][ty + i];
}

// ---------- GEMM C[m][n] = A[m][:] . Bt[n][:] + bias[n]; bf16 in, f32 acc ----------
// 128x128 block tile, 4 waves each 64x64 (4x4 MFMA 16x16x32 tiles), BK=32.
// OT = unsigned short (bf16 out) or float (f32 out).
template <typename OT>
__global__ __launch_bounds__(256) void gemm_bt(
    const unsigned short* __restrict__ A,   // [M][K] bf16 row-major
    const unsigned short* __restrict__ Bt,  // [N][K] bf16 row-major (pre-transposed B)
    const float* __restrict__ bias,         // [N] f32
    OT* __restrict__ C,                     // [M][ldc]
    int K, int ldc) {
  __shared__ unsigned short As[128 * 40];
  __shared__ unsigned short Bs[128 * 40];
  const int m0 = blockIdx.y * 128, n0 = blockIdx.x * 128;
  const int tid = threadIdx.x;
  const int lane = tid & 63, wave = tid >> 6;
  const int wm = (wave >> 1) * 64, wn = (wave & 1) * 64;
  const int quad = lane >> 4, l15 = lane & 15;
  const int ar = tid >> 2, ak = (tid & 3) * 8;

  f32x4 acc[4][4] = {};
  const unsigned short* Ap = A + (long)(m0 + ar) * K + ak;
  const unsigned short* Bp = Bt + (long)(n0 + ar) * K + ak;

  for (int kb = 0; kb < K; kb += 32) {
    __syncthreads();
    *(u16x8*)&As[ar * 40 + ak]        = *(const u16x8*)(Ap + kb);
    *(u16x8*)&As[(ar + 64) * 40 + ak] = *(const u16x8*)(Ap + (long)64 * K + kb);
    *(u16x8*)&Bs[ar * 40 + ak]        = *(const u16x8*)(Bp + kb);
    *(u16x8*)&Bs[(ar + 64) * 40 + ak] = *(const u16x8*)(Bp + (long)64 * K + kb);
    __syncthreads();
    bf16x8 af[4], bfr[4];
#pragma unroll
    for (int t = 0; t < 4; t++)
      af[t] = *(const bf16x8*)&As[(wm + t * 16 + l15) * 40 + quad * 8];
#pragma unroll
    for (int t = 0; t < 4; t++)
      bfr[t] = *(const bf16x8*)&Bs[(wn + t * 16 + l15) * 40 + quad * 8];
#pragma unroll
    for (int i = 0; i < 4; i++)
#pragma unroll
      for (int j = 0; j < 4; j++)
        acc[i][j] = __builtin_amdgcn_mfma_f32_16x16x32_bf16(af[i], bfr[j], acc[i][j], 0, 0, 0);
  }
#pragma unroll
  for (int j = 0; j < 4; j++) {
    int n = n0 + wn + j * 16 + l15;
    float bv = bias[n];
#pragma unroll
    for (int i = 0; i < 4; i++) {
      int mr = m0 + wm + i * 16 + quad * 4;
#pragma unroll
      for (int r = 0; r < 4; r++) {
        float v = acc[i][j][r] + bv;
        if constexpr (sizeof(OT) == 2)
          C[(long)(mr + r) * ldc + n] = f2bf(v);
        else
          C[(long)(mr + r) * ldc + n] = v;
      }
    }
  }
}

// ---------------- differential flash attention ----------------
// grid: (S/64, H, B); block 256 (4 waves, wave w owns q rows [w*16, w*16+16))
__global__ __launch_bounds__(256) void attn_k(
    const unsigned short* __restrict__ qkv,  // [B*S][6144] bf16 (q|k|v)
    const unsigned short* __restrict__ vt,   // [B][2048 hd][2048 s] bf16
    const float* __restrict__ mask,          // [B][S] f32
    const float* __restrict__ lamp,          // [1] f32
    unsigned short* __restrict__ out) {      // [B*S][2048] bf16
  const int S = 2048;
  __shared__ unsigned short q1s[64 * 64];
  __shared__ unsigned short q2s[64 * 64];
  __shared__ unsigned short k1s[64 * 72];
  __shared__ unsigned short k2s[64 * 72];
  __shared__ unsigned short vts[128 * 72];
  __shared__ unsigned short pls[4 * 16 * 72];
  __shared__ float maskf[64];

  const int b = blockIdx.z, h = blockIdx.y, q0 = blockIdx.x * 64;
  const int tid = threadIdx.x;
  const int lane = tid & 63, wave = tid >> 6;
  const int quad = lane >> 4, l15 = lane & 15;
  const long rowq = (long)(b * S + q0);
  const int sr = tid >> 3, dc = (tid & 7) * 8;

  { // stage Q tiles (64x64 q1, q2), read once, kept in regs
    const unsigned short* qb = qkv + rowq * 6144 + h * 64;
    *(u16x8*)&q1s[sr * 64 + dc]        = *(const u16x8*)&qb[(long)sr * 6144 + dc];
    *(u16x8*)&q1s[(sr + 32) * 64 + dc] = *(const u16x8*)&qb[(long)(sr + 32) * 6144 + dc];
    *(u16x8*)&q2s[sr * 64 + dc]        = *(const u16x8*)&qb[(long)sr * 6144 + 1024 + dc];
    *(u16x8*)&q2s[(sr + 32) * 64 + dc] = *(const u16x8*)&qb[(long)(sr + 32) * 6144 + 1024 + dc];
  }
  __syncthreads();
  bf16x8 aq1[2], aq2[2];
#pragma unroll
  for (int ks = 0; ks < 2; ks++) {
    aq1[ks] = *(const bf16x8*)&q1s[(wave * 16 + l15) * 64 + ks * 32 + quad * 8];
    aq2[ks] = *(const bf16x8*)&q2s[(wave * 16 + l15) * 64 + ks * 32 + quad * 8];
  }

  f32x4 o1[8] = {}, o2[8] = {};
  float m1[4], l1[4], m2[4], l2[4];
#pragma unroll
  for (int r = 0; r < 4; r++) { m1[r] = m2[r] = -INFINITY; l1[r] = l2[r] = 0.f; }

  const float scale = 0.08838834764831845f;  // 128^-0.5 (full head dim)
  unsigned short* pw = &pls[wave * 16 * 72];

  for (int kc0 = 0; kc0 < S; kc0 += 64) {
    __syncthreads();
    { // stage K1,K2 (64x64), Vt slice (128 d x 64 s), mask adds
      const unsigned short* kb = qkv + (long)(b * S + kc0) * 6144 + h * 64;
      *(u16x8*)&k1s[sr * 72 + dc]        = *(const u16x8*)&kb[(long)sr * 6144 + 2048 + dc];
      *(u16x8*)&k1s[(sr + 32) * 72 + dc] = *(const u16x8*)&kb[(long)(sr + 32) * 6144 + 2048 + dc];
      *(u16x8*)&k2s[sr * 72 + dc]        = *(const u16x8*)&kb[(long)sr * 6144 + 3072 + dc];
      *(u16x8*)&k2s[(sr + 32) * 72 + dc] = *(const u16x8*)&kb[(long)(sr + 32) * 6144 + 3072 + dc];
      const unsigned short* vb = vt + ((long)(b * 16 + h) * 128) * 2048 + kc0;
#pragma unroll
      for (int j2 = 0; j2 < 4; j2++)
        *(u16x8*)&vts[(sr + j2 * 32) * 72 + dc] =
            *(const u16x8*)&vb[(long)(sr + j2 * 32) * 2048 + dc];
      if (tid < 64) maskf[tid] = (1.f - mask[(long)b * S + kc0 + tid]) * -1e4f;
    }
    __syncthreads();

    // scores: s1 = q1.k1^T, s2 = q2.k2^T   (16q x 64k per wave)
    f32x4 s1[4] = {}, s2[4] = {};
#pragma unroll
    for (int nt = 0; nt < 4; nt++) {
#pragma unroll
      for (int ks = 0; ks < 2; ks++) {
        bf16x8 b1 = *(const bf16x8*)&k1s[(nt * 16 + l15) * 72 + ks * 32 + quad * 8];
        bf16x8 b2 = *(const bf16x8*)&k2s[(nt * 16 + l15) * 72 + ks * 32 + quad * 8];
        s1[nt] = __builtin_amdgcn_mfma_f32_16x16x32_bf16(aq1[ks], b1, s1[nt], 0, 0, 0);
        s2[nt] = __builtin_amdgcn_mfma_f32_16x16x32_bf16(aq2[ks], b2, s2[nt], 0, 0, 0);
      }
    }
    // scale + mask + row max (rows live across 16 lanes of each quad)
    float tm1[4], tm2[4];
#pragma unroll
    for (int r = 0; r < 4; r++) { tm1[r] = -INFINITY; tm2[r] = -INFINITY; }
#pragma unroll
    for (int nt = 0; nt < 4; nt++) {
      float ma = maskf[nt * 16 + l15];
#pragma unroll
      for (int r = 0; r < 4; r++) {
        s1[nt][r] = s1[nt][r] * scale + ma;
        s2[nt][r] = s2[nt][r] * scale + ma;
        tm1[r] = fmaxf(tm1[r], s1[nt][r]);
        tm2[r] = fmaxf(tm2[r], s2[nt][r]);
      }
    }
#pragma unroll
    for (int off = 1; off < 16; off <<= 1)
#pragma unroll
      for (int r = 0; r < 4; r++) {
        tm1[r] = fmaxf(tm1[r], __shfl_xor(tm1[r], off));
        tm2[r] = fmaxf(tm2[r], __shfl_xor(tm2[r], off));
      }
    float al1[4], al2[4], rs1[4], rs2[4];
#pragma unroll
    for (int r = 0; r < 4; r++) {
      float mn1 = fmaxf(m1[r], tm1[r]);
      al1[r] = exp2f((m1[r] - mn1) * LOG2E); m1[r] = mn1;
      float mn2 = fmaxf(m2[r], tm2[r]);
      al2[r] = exp2f((m2[r] - mn2) * LOG2E); m2[r] = mn2;
      rs1[r] = 0.f; rs2[r] = 0.f;
    }
#pragma unroll
    for (int nt = 0; nt < 4; nt++)
#pragma unroll
      for (int r = 0; r < 4; r++) {
        float p1 = exp2f((s1[nt][r] - m1[r]) * LOG2E);
        float p2 = exp2f((s2[nt][r] - m2[r]) * LOG2E);
        s1[nt][r] = p1; s2[nt][r] = p2;
        rs1[r] += p1; rs2[r] += p2;
      }
#pragma unroll
    for (int off = 1; off < 16; off <<= 1)
#pragma unroll
      for (int r = 0; r < 4; r++) {
        rs1[r] += __shfl_xor(rs1[r], off);
        rs2[r] += __shfl_xor(rs2[r], off);
      }
#pragma unroll
    for (int r = 0; r < 4; r++) {
      l1[r] = l1[r] * al1[r] + rs1[r];
      l2[r] = l2[r] * al2[r] + rs2[r];
    }
#pragma unroll
    for (int dn = 0; dn < 8; dn++)
#pragma unroll
      for (int r = 0; r < 4; r++) {
        o1[dn][r] *= al1[r];
        o2[dn][r] *= al2[r];
      }
    // P: C-layout -> A-layout via wave-private LDS (in-wave DS ops are in-order;
    // asm barrier keeps the compiler from reordering and drains lgkm).
    bf16x8 ap1[2], ap2[2];
#pragma unroll
    for (int nt = 0; nt < 4; nt++)
#pragma unroll
      for (int r = 0; r < 4; r++)
        pw[(quad * 4 + r) * 72 + nt * 16 + l15] = f2bf(s1[nt][r]);
    asm volatile("s_waitcnt lgkmcnt(0)" ::: "memory");
#pragma unroll
    for (int ks = 0; ks < 2; ks++)
      ap1[ks] = *(const bf16x8*)&pw[l15 * 72 + ks * 32 + quad * 8];
    asm volatile("s_waitcnt lgkmcnt(0)" ::: "memory");
#pragma unroll
    for (int nt = 0; nt < 4; nt++)
#pragma unroll
      for (int r = 0; r < 4; r++)
        pw[(quad * 4 + r) * 72 + nt * 16 + l15] = f2bf(s2[nt][r]);
    asm volatile("s_waitcnt lgkmcnt(0)" ::: "memory");
#pragma unroll
    for (int ks = 0; ks < 2; ks++)
      ap2[ks] = *(const bf16x8*)&pw[l15 * 72 + ks * 32 + quad * 8];
    // PV: shared V b-frags feed both accumulators
#pragma unroll
    for (int ks = 0; ks < 2; ks++)
#pragma unroll
      for (int dn = 0; dn < 8; dn++) {
        bf16x8 bv = *(const bf16x8*)&vts[(dn * 16 + l15) * 72 + ks * 32 + quad * 8];
        o1[dn] = __builtin_amdgcn_mfma_f32_16x16x32_bf16(ap1[ks], bv, o1[dn], 0, 0, 0);
        o2[dn] = __builtin_amdgcn_mfma_f32_16x16x32_bf16(ap2[ks], bv, o2[dn], 0, 0, 0);
      }
  }
  // epilogue: out = O1/l1 - lambda * O2/l2
  float lam = lamp[0];
#pragma unroll
  for (int dn = 0; dn < 8; dn++)
#pragma unroll
    for (int r = 0; r < 4; r++) {
      float v = o1[dn][r] / l1[r] - lam * o2[dn][r] / l2[r];
      out[(rowq + wave * 16 + quad * 4 + r) * 2048 + h * 128 + dn * 16 + l15] = f2bf(v);
    }
}

extern "C" void kernel_launch(void* const* d_in, const int* in_sizes, int n_in,
                              void* d_out, int out_size, void* d_ws, size_t ws_size,
                              hipStream_t stream) {
  (void)in_sizes; (void)n_in; (void)out_size; (void)ws_size;
  const float* hs   = (const float*)d_in[0];
  const float* mask = (const float*)d_in[1];
  const float* Wa   = (const float*)d_in[2];
  const float* ba   = (const float*)d_in[3];
  const float* Wp   = (const float*)d_in[4];
  const float* bp   = (const float*)d_in[5];
  const float* lam  = (const float*)d_in[6];
  float* out = (float*)d_out;
  unsigned short* ws = (unsigned short*)d_ws;

  // workspace layout (bf16 elems): 67,108,864 elems = 128 MiB
  unsigned short* hsb = ws;                                  // [4096][2048]
  unsigned short* WtA = hsb + (long)4096 * 2048;             // [6144][2048]
  unsigned short* WtP = WtA + (long)6144 * 2048;             // [2048][2048]
  unsigned short* qkv = WtP + (long)2048 * 2048;             // [4096][6144]
  unsigned short* Vt  = qkv + (long)4096 * 6144;             // [2][2048 hd][2048 s]
  unsigned short* att = Vt + (long)2 * 2048 * 2048;          // [4096][2048]

  // 1) cast hs to bf16; pre-transpose+cast weights to [N][K] bf16
  cvt_bf16_k<<<4096, 256, 0, stream>>>(hs, hsb, (long)4096 * 2048);
  cvt_transpose_k<<<dim3(6144 / 32, 2048 / 32), 256, 0, stream>>>(Wa, WtA, 6144, 2048);
  cvt_transpose_k<<<dim3(2048 / 32, 2048 / 32), 256, 0, stream>>>(Wp, WtP, 2048, 2048);
  // 2) qkv = hs @ W_attn + b_attn  (bf16 out)
  gemm_bt<unsigned short><<<dim3(6144 / 128, 4096 / 128), 256, 0, stream>>>(
      hsb, WtA, ba, qkv, 2048, 6144);
  // 3) transpose V part per batch: Vt[b][hd][s]
  transpose_k<<<dim3(2048 / 32, 2048 / 32, 2), 256, 0, stream>>>(
      qkv + 4096, Vt, 6144, 2048, (long)2048 * 6144, (long)2048 * 2048);
  // 4) differential flash attention (bf16 out)
  attn_k<<<dim3(2048 / 64, 16, 2), 256, 0, stream>>>(qkv, Vt, mask, lam, att);
  // 5) out = att @ W_proj + b_proj  (f32 out)
  gemm_bt<float><<<dim3(2048 / 128, 4096 / 128), 256, 0, stream>>>(
      att, WtP, bp, out, 2048, 2048);
}

// Round 3
// 651.077 us; speedup vs baseline: 1.3895x; 1.3895x over previous
//
#include <hip/hip_runtime.h>
#include <hip/hip_bf16.h>

typedef __attribute__((ext_vector_type(8))) short bf16x8;
typedef __attribute__((ext_vector_type(8))) unsigned short u16x8;
typedef __attribute__((ext_vector_type(4))) float f32x4;

#define LOG2E 1.4426950408889634f

__device__ __forceinline__ unsigned short f2bf(float f) {
  union { float f; unsigned int i; } v; v.f = f;
  unsigned int r = v.i + 0x7FFFu + ((v.i >> 16) & 1u);  // RNE
  return (unsigned short)(r >> 16);
}
__device__ __forceinline__ unsigned int pack2bf(float a, float b) {
  return (unsigned int)f2bf(a) | ((unsigned int)f2bf(b) << 16);
}
// async global->LDS, 16B per lane; LDS dest = wave-uniform base + lane*16
__device__ __forceinline__ void gll16(const unsigned short* g, unsigned short* l) {
  __builtin_amdgcn_global_load_lds(
      (const __attribute__((address_space(1))) unsigned int*)g,
      (__attribute__((address_space(3))) unsigned int*)l, 16, 0, 0);
}

// ---------------- f32 -> bf16 straight cast ----------------
__global__ void cvt_bf16_k(const float* __restrict__ in, unsigned short* __restrict__ out,
                           long n) {
  long i = ((long)blockIdx.x * 256 + threadIdx.x) * 8;
  if (i + 8 > n) return;
  float4 a = *(const float4*)(in + i);
  float4 b = *(const float4*)(in + i + 4);
  u16x8 o;
  o[0] = f2bf(a.x); o[1] = f2bf(a.y); o[2] = f2bf(a.z); o[3] = f2bf(a.w);
  o[4] = f2bf(b.x); o[5] = f2bf(b.y); o[6] = f2bf(b.z); o[7] = f2bf(b.w);
  *(u16x8*)(out + i) = o;
}

// ---------------- f32 in -> bf16 out, transposed ----------------
__global__ void cvt_transpose_k(const float* __restrict__ in, unsigned short* __restrict__ out,
                                long in_rs, long out_rs) {
  __shared__ unsigned short tile[32][33];
  int c0 = blockIdx.x * 32, r0 = blockIdx.y * 32;
  int tx = threadIdx.x & 31, ty = threadIdx.x >> 5;
#pragma unroll
  for (int i = 0; i < 32; i += 8)
    tile[ty + i][tx] = f2bf(in[(long)(r0 + ty + i) * in_rs + c0 + tx]);
  __syncthreads();
#pragma unroll
  for (int i = 0; i < 32; i += 8)
    out[(long)(c0 + ty + i) * out_rs + r0 + tx] = tile[tx][ty + i];
}

// ---------------- bf16 transpose ----------------
__global__ void transpose_k(const unsigned short* __restrict__ in,
                            unsigned short* __restrict__ out,
                            long in_rs, long out_rs, long in_zoff, long out_zoff) {
  __shared__ unsigned short tile[32][33];
  const unsigned short* ip = in + (long)blockIdx.z * in_zoff;
  unsigned short* op = out + (long)blockIdx.z * out_zoff;
  int c0 = blockIdx.x * 32, r0 = blockIdx.y * 32;
  int tx = threadIdx.x & 31, ty = threadIdx.x >> 5;
#pragma unroll
  for (int i = 0; i < 32; i += 8)
    tile[ty + i][tx] = ip[(long)(r0 + ty + i) * in_rs + c0 + tx];
  __syncthreads();
#pragma unroll
  for (int i = 0; i < 32; i += 8)
    op[(long)(c0 + ty + i) * out_rs + r0 + tx] = tile[tx][ty + i];
}

// ---- pack V^T per (b,h) into tile-major, LDS-image XOR-swizzled layout ----
// Vp[(b,h,t)][d=128][pchunk=8] ; chunk c of row d stored at p = c ^ (d&7)
__global__ void vpack_k(const unsigned short* __restrict__ vt, unsigned short* __restrict__ vp) {
  const int t = blockIdx.x, h = blockIdx.y, b = blockIdx.z, tid = threadIdx.x;
  const int d = tid >> 1;
  const long tile = ((long)(b * 16 + h) * 32 + t) * 8192;
  const unsigned short* src = vt + ((long)b * 2048 + h * 128 + d) * 2048 + t * 64;
#pragma unroll
  for (int i = 0; i < 4; i++) {
    int cc = (tid & 1) * 4 + i;
    u16x8 v = *(const u16x8*)(src + cc * 8);
    *(u16x8*)(vp + tile + d * 64 + ((cc ^ (d & 7)) * 8)) = v;
  }
}

// ---- pack K1/K2 per (b,h) tiles, swizzled: chunk c of row s stored at c^(s&7) ----
__global__ void kpack_k(const unsigned short* __restrict__ qkv,
                        unsigned short* __restrict__ k1p, unsigned short* __restrict__ k2p) {
  const int t = blockIdx.x, h = blockIdx.y, b = blockIdx.z, tid = threadIdx.x;
  const long tile = ((long)(b * 16 + h) * 32 + t) * 4096;
#pragma unroll
  for (int rd = 0; rd < 2; rd++) {
    int row = rd * 32 + (tid >> 3);
    int c = tid & 7;
    const unsigned short* src = qkv + ((long)b * 2048 + t * 64 + row) * 6144 + h * 64 + c * 8;
    long dst = tile + row * 64 + ((c ^ (row & 7)) * 8);
    *(u16x8*)(k1p + dst) = *(const u16x8*)(src + 2048);
    *(u16x8*)(k2p + dst) = *(const u16x8*)(src + 3072);
  }
}

// ---------- GEMM (m97 structure): C = A . Bt^T + bias, bf16 in, f32 acc ----------
template <typename OT>
__global__ __launch_bounds__(256) void gemm_bt(
    const unsigned short* __restrict__ A,   // [M][K]
    const unsigned short* __restrict__ Bt,  // [N][K]
    const float* __restrict__ bias,         // [N]
    OT* __restrict__ C, int K, int ldc) {
  __shared__ unsigned short As[128 * 32];
  __shared__ unsigned short Bs[128 * 32];
  const int m0 = blockIdx.y * 128, n0 = blockIdx.x * 128;
  const int tid = threadIdx.x, lane = tid & 63, wave = tid >> 6;
  const int wm = (wave >> 1) * 64, wn = (wave & 1) * 64;
  const int quad = lane >> 4, l15 = lane & 15;
  const int ar = tid >> 2, ak = (tid & 3) * 8;

  f32x4 acc[4][4] = {};
  const unsigned short* Ap = A + (long)(m0 + ar) * K + ak;
  const unsigned short* Bp = Bt + (long)(n0 + ar) * K + ak;
  unsigned short* AsW = As + wave * 512;
  unsigned short* BsW = Bs + wave * 512;

  for (int kb = 0; kb < K; kb += 32) {
    __syncthreads();
    gll16(Ap + kb, AsW);
    gll16(Ap + (long)64 * K + kb, AsW + 2048);
    gll16(Bp + kb, BsW);
    gll16(Bp + (long)64 * K + kb, BsW + 2048);
    __syncthreads();
    bf16x8 af[4], bfr[4];
#pragma unroll
    for (int t = 0; t < 4; t++)
      af[t] = *(const bf16x8*)&As[(wm + t * 16 + l15) * 32 + quad * 8];
#pragma unroll
    for (int t = 0; t < 4; t++)
      bfr[t] = *(const bf16x8*)&Bs[(wn + t * 16 + l15) * 32 + quad * 8];
#pragma unroll
    for (int i = 0; i < 4; i++)
#pragma unroll
      for (int j = 0; j < 4; j++)
        acc[i][j] = __builtin_amdgcn_mfma_f32_16x16x32_bf16(af[i], bfr[j], acc[i][j], 0, 0, 0);
  }
#pragma unroll
  for (int j = 0; j < 4; j++) {
    int n = n0 + wn + j * 16 + l15;
    float bv = bias[n];
#pragma unroll
    for (int i = 0; i < 4; i++) {
      int mr = m0 + wm + i * 16 + quad * 4;
#pragma unroll
      for (int r = 0; r < 4; r++) {
        float v = acc[i][j][r] + bv;
        if constexpr (sizeof(OT) == 2)
          C[(long)(mr + r) * ldc + n] = f2bf(v);
        else
          C[(long)(mr + r) * ldc + n] = v;
      }
    }
  }
}

// ---------------- differential flash attention (S^T form) ----------------
// grid (32,16,2), block 256. Wave w owns q rows [w*16,w*16+16) via col=lane&15.
__global__ __launch_bounds__(256, 3) void attn_k(
    const unsigned short* __restrict__ qkv,  // [B*S][6144] (q|k|v) bf16
    const unsigned short* __restrict__ k1p,  // packed swizzled tiles
    const unsigned short* __restrict__ k2p,
    const unsigned short* __restrict__ vp,
    const float* __restrict__ mask,          // [B][S] f32
    const float* __restrict__ lamp,          // [1] f32
    unsigned short* __restrict__ out) {      // [B*S][2048] bf16
  __shared__ unsigned short k1s[64 * 64];
  __shared__ unsigned short k2s[64 * 64];
  __shared__ unsigned short vts[128 * 64];
  const int b = blockIdx.z, h = blockIdx.y, q0 = blockIdx.x * 64;
  const int tid = threadIdx.x, lane = tid & 63, wave = tid >> 6;
  const int quad = lane >> 4, l15 = lane & 15;
  const long rowq = (long)b * 2048 + q0;
  const int sw = l15 & 7;

  // Q fragments (B-operand layout) straight from global
  bf16x8 aq1[2], aq2[2];
  {
    const unsigned short* qr = qkv + (rowq + wave * 16 + l15) * 6144 + h * 64 + quad * 8;
    aq1[0] = *(const bf16x8*)qr;
    aq1[1] = *(const bf16x8*)(qr + 32);
    aq2[0] = *(const bf16x8*)(qr + 1024);
    aq2[1] = *(const bf16x8*)(qr + 1056);
  }
  f32x4 o1[8] = {}, o2[8] = {};
  float m1 = -INFINITY, l1 = 0.f, m2 = -INFINITY, l2 = 0.f;
  const float scale = 0.08838834764831845f;  // 128^-0.5
  const long tb = (long)(b * 16 + h) * 32;
  const int src0 = ((quad & 1) << 5) | l15;
  const int src1 = src0 | 16;
  const bool hisel = (quad & 2) != 0;

  for (int t = 0; t < 32; t++) {
    __syncthreads();
    {
      const unsigned short* k1t = k1p + (tb + t) * 4096 + tid * 8;
      const unsigned short* k2t = k2p + (tb + t) * 4096 + tid * 8;
      const unsigned short* vtt = vp + (tb + t) * 8192 + tid * 8;
      gll16(k1t, k1s + wave * 512);
      gll16(k1t + 2048, k1s + 2048 + wave * 512);
      gll16(k2t, k2s + wave * 512);
      gll16(k2t + 2048, k2s + 2048 + wave * 512);
#pragma unroll
      for (int rr = 0; rr < 4; rr++)
        gll16(vtt + rr * 2048, vts + rr * 2048 + wave * 512);
    }
    float4 mq[4];
#pragma unroll
    for (int nt = 0; nt < 4; nt++)
      mq[nt] = *(const float4*)(mask + (long)b * 2048 + t * 64 + nt * 16 + quad * 4);
    __syncthreads();

    // S^T = K . Q^T : C row = k (quad*4+r), col = q (l15)
    f32x4 s1[4] = {}, s2[4] = {};
#pragma unroll
    for (int nt = 0; nt < 4; nt++) {
      const int row = (nt * 16 + l15) * 64;
#pragma unroll
      for (int ks = 0; ks < 2; ks++) {
        const int p = ((ks * 4 + quad) ^ sw) * 8;
        bf16x8 kf1 = *(const bf16x8*)&k1s[row + p];
        bf16x8 kf2 = *(const bf16x8*)&k2s[row + p];
        s1[nt] = __builtin_amdgcn_mfma_f32_16x16x32_bf16(kf1, aq1[ks], s1[nt], 0, 0, 0);
        s2[nt] = __builtin_amdgcn_mfma_f32_16x16x32_bf16(kf2, aq2[ks], s2[nt], 0, 0, 0);
      }
    }
    // scale + mask; row stats: in-lane reduce over 16 + 2 cross-quad shuffles
    float tm1 = -INFINITY, tm2 = -INFINITY;
#pragma unroll
    for (int nt = 0; nt < 4; nt++)
#pragma unroll
      for (int r = 0; r < 4; r++) {
        float ma = fmaf(((const float*)&mq[nt])[r], 1e4f, -1e4f);  // (1-m)*-1e4
        s1[nt][r] = fmaf(s1[nt][r], scale, ma);
        s2[nt][r] = fmaf(s2[nt][r], scale, ma);
        tm1 = fmaxf(tm1, s1[nt][r]);
        tm2 = fmaxf(tm2, s2[nt][r]);
      }
    tm1 = fmaxf(tm1, __shfl_xor(tm1, 16, 64)); tm1 = fmaxf(tm1, __shfl_xor(tm1, 32, 64));
    tm2 = fmaxf(tm2, __shfl_xor(tm2, 16, 64)); tm2 = fmaxf(tm2, __shfl_xor(tm2, 32, 64));
    float mn1 = fmaxf(m1, tm1), mn2 = fmaxf(m2, tm2);
    float al1 = exp2f((m1 - mn1) * LOG2E), al2 = exp2f((m2 - mn2) * LOG2E);
    m1 = mn1; m2 = mn2;
    float rs1 = 0.f, rs2 = 0.f;
#pragma unroll
    for (int nt = 0; nt < 4; nt++)
#pragma unroll
      for (int r = 0; r < 4; r++) {
        float p1 = exp2f((s1[nt][r] - m1) * LOG2E);
        float p2 = exp2f((s2[nt][r] - m2) * LOG2E);
        s1[nt][r] = p1; s2[nt][r] = p2;
        rs1 += p1; rs2 += p2;
      }
    rs1 += __shfl_xor(rs1, 16, 64); rs1 += __shfl_xor(rs1, 32, 64);
    rs2 += __shfl_xor(rs2, 16, 64); rs2 += __shfl_xor(rs2, 32, 64);
    l1 = l1 * al1 + rs1; l2 = l2 * al2 + rs2;
#pragma unroll
    for (int dn = 0; dn < 8; dn++)
#pragma unroll
      for (int r = 0; r < 4; r++) { o1[dn][r] *= al1; o2[dn][r] *= al2; }

    // P^T C-layout -> B-operand layout, in-register via bpermute
    unsigned int w1[4][2], w2[4][2];
#pragma unroll
    for (int nt = 0; nt < 4; nt++) {
      w1[nt][0] = pack2bf(s1[nt][0], s1[nt][1]);
      w1[nt][1] = pack2bf(s1[nt][2], s1[nt][3]);
      w2[nt][0] = pack2bf(s2[nt][0], s2[nt][1]);
      w2[nt][1] = pack2bf(s2[nt][2], s2[nt][3]);
    }
#pragma unroll
    for (int c = 0; c < 2; c++) {
      union { bf16x8 v; unsigned int u[4]; } f1, f2;
#pragma unroll
      for (int a = 0; a < 2; a++) {
        int sl = a ? src1 : src0;
#pragma unroll
        for (int m = 0; m < 2; m++) {
          unsigned int lo1 = __shfl(w1[2 * c][m], sl, 64);
          unsigned int hi1 = __shfl(w1[2 * c + 1][m], sl, 64);
          f1.u[a * 2 + m] = hisel ? hi1 : lo1;
          unsigned int lo2 = __shfl(w2[2 * c][m], sl, 64);
          unsigned int hi2 = __shfl(w2[2 * c + 1][m], sl, 64);
          f2.u[a * 2 + m] = hisel ? hi2 : lo2;
        }
      }
      // O^T += V^T . P^T  (A = V frag from LDS, shared by both streams)
#pragma unroll
      for (int dn = 0; dn < 8; dn++) {
        const int p = ((c * 4 + quad) ^ sw) * 8;
        bf16x8 vf = *(const bf16x8*)&vts[(dn * 16 + l15) * 64 + p];
        o1[dn] = __builtin_amdgcn_mfma_f32_16x16x32_bf16(vf, f1.v, o1[dn], 0, 0, 0);
        o2[dn] = __builtin_amdgcn_mfma_f32_16x16x32_bf16(vf, f2.v, o2[dn], 0, 0, 0);
      }
    }
  }
  // epilogue: out = O1/l1 - lam*O2/l2 ; O^T: row d = dn*16+quad*4+r, col q = l15
  float lam = lamp[0];
  float i1 = 1.f / l1, i2 = lam / l2;
  unsigned short* orow = out + (rowq + wave * 16 + l15) * 2048 + h * 128 + quad * 4;
#pragma unroll
  for (int dn = 0; dn < 8; dn++) {
    uint2 st;
    st.x = pack2bf(o1[dn][0] * i1 - o2[dn][0] * i2, o1[dn][1] * i1 - o2[dn][1] * i2);
    st.y = pack2bf(o1[dn][2] * i1 - o2[dn][2] * i2, o1[dn][3] * i1 - o2[dn][3] * i2);
    *(uint2*)(orow + dn * 16) = st;
  }
}

extern "C" void kernel_launch(void* const* d_in, const int* in_sizes, int n_in,
                              void* d_out, int out_size, void* d_ws, size_t ws_size,
                              hipStream_t stream) {
  (void)in_sizes; (void)n_in; (void)out_size; (void)ws_size;
  const float* hs   = (const float*)d_in[0];
  const float* mask = (const float*)d_in[1];
  const float* Wa   = (const float*)d_in[2];
  const float* ba   = (const float*)d_in[3];
  const float* Wp   = (const float*)d_in[4];
  const float* bp   = (const float*)d_in[5];
  const float* lam  = (const float*)d_in[6];
  float* out = (float*)d_out;
  unsigned short* ws = (unsigned short*)d_ws;

  // workspace layout (bf16 elems), total exactly 67,108,864 = 128 MiB
  unsigned short* hsb = ws;                                  // [4096][2048]  (aliased by att)
  unsigned short* WtA = hsb + (long)4096 * 2048;             // [6144][2048]  (aliased by Vt)
  unsigned short* WtP = WtA + (long)6144 * 2048;             // [2048][2048]
  unsigned short* qkv = WtP + (long)2048 * 2048;             // [4096][6144]
  unsigned short* K1p = qkv + (long)4096 * 6144;             // 2*16*32 tiles * 4096
  unsigned short* K2p = K1p + (long)2 * 16 * 2048 * 64;
  unsigned short* Vp  = K2p + (long)2 * 16 * 2048 * 64;      // 2*16*32 tiles * 8192
  unsigned short* Vt  = WtA;                                 // alias (WtA dead after step 4)
  unsigned short* att = hsb;                                 // alias (hsb dead after step 4)

  // 1) casts / weight transposes
  cvt_bf16_k<<<4096, 256, 0, stream>>>(hs, hsb, (long)4096 * 2048);
  cvt_transpose_k<<<dim3(192, 64), 256, 0, stream>>>(Wa, WtA, 6144, 2048);
  cvt_transpose_k<<<dim3(64, 64), 256, 0, stream>>>(Wp, WtP, 2048, 2048);
  // 2) qkv = hs @ W_attn + b_attn (bf16 out)
  gemm_bt<unsigned short><<<dim3(48, 32), 256, 0, stream>>>(hsb, WtA, ba, qkv, 2048, 6144);
  // 3) V transpose + per-head packs (swizzled LDS images)
  transpose_k<<<dim3(64, 64, 2), 256, 0, stream>>>(
      qkv + 4096, Vt, 6144, 2048, (long)2048 * 6144, (long)2048 * 2048);
  vpack_k<<<dim3(32, 16, 2), 256, 0, stream>>>(Vt, Vp);
  kpack_k<<<dim3(32, 16, 2), 256, 0, stream>>>(qkv, K1p, K2p);
  // 4) differential flash attention
  attn_k<<<dim3(32, 16, 2), 256, 0, stream>>>(qkv, K1p, K2p, Vp, mask, lam, att);
  // 5) out = att @ W_proj + b_proj (f32 out)
  gemm_bt<float><<<dim3(16, 32), 256, 0, stream>>>(att, WtP, bp, out, 2048, 2048);
}

// Round 4
// 552.957 us; speedup vs baseline: 1.6361x; 1.1774x over previous
//
#include <hip/hip_runtime.h>
#include <hip/hip_bf16.h>

typedef __attribute__((ext_vector_type(8))) short bf16x8;
typedef __attribute__((ext_vector_type(8))) unsigned short u16x8;
typedef __attribute__((ext_vector_type(4))) float f32x4;

__device__ __forceinline__ unsigned short f2bf(float f) {
  union { float f; unsigned int i; } v; v.f = f;
  unsigned int r = v.i + 0x7FFFu + ((v.i >> 16) & 1u);  // RNE
  return (unsigned short)(r >> 16);
}
// fast round-to-nearest (ties-away) pack of two f32 -> packed bf16x2
__device__ __forceinline__ unsigned int pack2bf_rn(float a, float b) {
  union { float f; unsigned int i; } x, y; x.f = a; y.f = b;
  return ((x.i + 0x8000u) >> 16) | ((y.i + 0x8000u) & 0xFFFF0000u);
}
// async global->LDS, 16B per lane; LDS dest = wave-uniform base + lane*16
__device__ __forceinline__ void gll16(const unsigned short* g, unsigned short* l) {
  __builtin_amdgcn_global_load_lds(
      (const __attribute__((address_space(1))) unsigned int*)g,
      (__attribute__((address_space(3))) unsigned int*)l, 16, 0, 0);
}

// ---------------- f32 -> bf16 straight cast ----------------
__global__ void cvt_bf16_k(const float* __restrict__ in, unsigned short* __restrict__ out,
                           long n) {
  long i = ((long)blockIdx.x * 256 + threadIdx.x) * 8;
  if (i + 8 > n) return;
  float4 a = *(const float4*)(in + i);
  float4 b = *(const float4*)(in + i + 4);
  u16x8 o;
  o[0] = f2bf(a.x); o[1] = f2bf(a.y); o[2] = f2bf(a.z); o[3] = f2bf(a.w);
  o[4] = f2bf(b.x); o[5] = f2bf(b.y); o[6] = f2bf(b.z); o[7] = f2bf(b.w);
  *(u16x8*)(out + i) = o;
}

// ---------------- f32 in -> bf16 out, transposed ----------------
__global__ void cvt_transpose_k(const float* __restrict__ in, unsigned short* __restrict__ out,
                                long in_rs, long out_rs) {
  __shared__ unsigned short tile[32][33];
  int c0 = blockIdx.x * 32, r0 = blockIdx.y * 32;
  int tx = threadIdx.x & 31, ty = threadIdx.x >> 5;
#pragma unroll
  for (int i = 0; i < 32; i += 8)
    tile[ty + i][tx] = f2bf(in[(long)(r0 + ty + i) * in_rs + c0 + tx]);
  __syncthreads();
#pragma unroll
  for (int i = 0; i < 32; i += 8)
    out[(long)(c0 + ty + i) * out_rs + r0 + tx] = tile[tx][ty + i];
}

// ---------------- bf16 transpose ----------------
__global__ void transpose_k(const unsigned short* __restrict__ in,
                            unsigned short* __restrict__ out,
                            long in_rs, long out_rs, long in_zoff, long out_zoff) {
  __shared__ unsigned short tile[32][33];
  const unsigned short* ip = in + (long)blockIdx.z * in_zoff;
  unsigned short* op = out + (long)blockIdx.z * out_zoff;
  int c0 = blockIdx.x * 32, r0 = blockIdx.y * 32;
  int tx = threadIdx.x & 31, ty = threadIdx.x >> 5;
#pragma unroll
  for (int i = 0; i < 32; i += 8)
    tile[ty + i][tx] = ip[(long)(r0 + ty + i) * in_rs + c0 + tx];
  __syncthreads();
#pragma unroll
  for (int i = 0; i < 32; i += 8)
    op[(long)(c0 + ty + i) * out_rs + r0 + tx] = tile[tx][ty + i];
}

// ---- pack V^T per (b,h) into tile-major, LDS-image XOR-swizzled layout ----
__global__ void vpack_k(const unsigned short* __restrict__ vt, unsigned short* __restrict__ vp) {
  const int t = blockIdx.x, h = blockIdx.y, b = blockIdx.z, tid = threadIdx.x;
  const int d = tid >> 1;
  const long tile = ((long)(b * 16 + h) * 32 + t) * 8192;
  const unsigned short* src = vt + ((long)b * 2048 + h * 128 + d) * 2048 + t * 64;
#pragma unroll
  for (int i = 0; i < 4; i++) {
    int cc = (tid & 1) * 4 + i;
    u16x8 v = *(const u16x8*)(src + cc * 8);
    *(u16x8*)(vp + tile + d * 64 + ((cc ^ (d & 7)) * 8)) = v;
  }
}

// ---- pack K1/K2 per (b,h) tiles, swizzled: chunk c of row s stored at c^(s&7) ----
__global__ void kpack_k(const unsigned short* __restrict__ qkv,
                        unsigned short* __restrict__ k1p, unsigned short* __restrict__ k2p) {
  const int t = blockIdx.x, h = blockIdx.y, b = blockIdx.z, tid = threadIdx.x;
  const long tile = ((long)(b * 16 + h) * 32 + t) * 4096;
#pragma unroll
  for (int rd = 0; rd < 2; rd++) {
    int row = rd * 32 + (tid >> 3);
    int c = tid & 7;
    const unsigned short* src = qkv + ((long)b * 2048 + t * 64 + row) * 6144 + h * 64 + c * 8;
    long dst = tile + row * 64 + ((c ^ (row & 7)) * 8);
    *(u16x8*)(k1p + dst) = *(const u16x8*)(src + 2048);
    *(u16x8*)(k2p + dst) = *(const u16x8*)(src + 3072);
  }
}

// ---------- GEMM (m97 structure): C = A . Bt^T + bias, bf16 in, f32 acc ----------
template <typename OT>
__global__ __launch_bounds__(256) void gemm_bt(
    const unsigned short* __restrict__ A,   // [M][K]
    const unsigned short* __restrict__ Bt,  // [N][K]
    const float* __restrict__ bias,         // [N]
    OT* __restrict__ C, int K, int ldc) {
  __shared__ unsigned short As[128 * 32];
  __shared__ unsigned short Bs[128 * 32];
  const int m0 = blockIdx.y * 128, n0 = blockIdx.x * 128;
  const int tid = threadIdx.x, lane = tid & 63, wave = tid >> 6;
  const int wm = (wave >> 1) * 64, wn = (wave & 1) * 64;
  const int quad = lane >> 4, l15 = lane & 15;
  const int ar = tid >> 2, ak = (tid & 3) * 8;

  f32x4 acc[4][4] = {};
  const unsigned short* Ap = A + (long)(m0 + ar) * K + ak;
  const unsigned short* Bp = Bt + (long)(n0 + ar) * K + ak;
  unsigned short* AsW = As + wave * 512;
  unsigned short* BsW = Bs + wave * 512;

  for (int kb = 0; kb < K; kb += 32) {
    __syncthreads();
    gll16(Ap + kb, AsW);
    gll16(Ap + (long)64 * K + kb, AsW + 2048);
    gll16(Bp + kb, BsW);
    gll16(Bp + (long)64 * K + kb, BsW + 2048);
    __syncthreads();
    bf16x8 af[4], bfr[4];
#pragma unroll
    for (int t = 0; t < 4; t++)
      af[t] = *(const bf16x8*)&As[(wm + t * 16 + l15) * 32 + quad * 8];
#pragma unroll
    for (int t = 0; t < 4; t++)
      bfr[t] = *(const bf16x8*)&Bs[(wn + t * 16 + l15) * 32 + quad * 8];
#pragma unroll
    for (int i = 0; i < 4; i++)
#pragma unroll
      for (int j = 0; j < 4; j++)
        acc[i][j] = __builtin_amdgcn_mfma_f32_16x16x32_bf16(af[i], bfr[j], acc[i][j], 0, 0, 0);
  }
#pragma unroll
  for (int j = 0; j < 4; j++) {
    int n = n0 + wn + j * 16 + l15;
    float bv = bias[n];
#pragma unroll
    for (int i = 0; i < 4; i++) {
      int mr = m0 + wm + i * 16 + quad * 4;
#pragma unroll
      for (int r = 0; r < 4; r++) {
        float v = acc[i][j][r] + bv;
        if constexpr (sizeof(OT) == 2)
          C[(long)(mr + r) * ldc + n] = f2bf(v);
        else
          C[(long)(mr + r) * ldc + n] = v;
      }
    }
  }
}

// ---------------- differential flash attention (S^T form, double-buffered) ----------------
// grid (32,16,2), block 256. Wave w owns q rows [w*16,w*16+16) via col=lane&15.
__global__ __launch_bounds__(256, 2) void attn_k(
    const unsigned short* __restrict__ qkv,  // [B*S][6144] (q|k|v) bf16
    const unsigned short* __restrict__ k1p,  // packed swizzled tiles
    const unsigned short* __restrict__ k2p,
    const unsigned short* __restrict__ vp,
    const float* __restrict__ mask,          // [B][S] f32
    const float* __restrict__ lamp,          // [1] f32
    unsigned short* __restrict__ out) {      // [B*S][2048] bf16
  __shared__ unsigned short k1s[2 * 4096];
  __shared__ unsigned short k2s[2 * 4096];
  __shared__ unsigned short vts[2 * 8192];
  __shared__ unsigned short pls[4 * 2 * 1024];  // [wave][stream][q16][k64] swizzled
  const int b = blockIdx.z, h = blockIdx.y, q0 = blockIdx.x * 64;
  const int tid = threadIdx.x, lane = tid & 63, wave = tid >> 6;
  const int quad = lane >> 4, l15 = lane & 15;
  const long rowq = (long)b * 2048 + q0;
  const int sw = l15 & 7;

  // Q fragments (B-operand layout) straight from global
  bf16x8 aq1[2], aq2[2];
  {
    const unsigned short* qr = qkv + (rowq + wave * 16 + l15) * 6144 + h * 64 + quad * 8;
    aq1[0] = *(const bf16x8*)qr;
    aq1[1] = *(const bf16x8*)(qr + 32);
    aq2[0] = *(const bf16x8*)(qr + 1024);
    aq2[1] = *(const bf16x8*)(qr + 1056);
  }
  f32x4 o1[8] = {}, o2[8] = {};
  float m1 = -INFINITY, l1 = 0.f, m2 = -INFINITY, l2 = 0.f;
  // log2e-scaled domain: score' = s*(scale*log2e) + (1-mask)*(-1e4*log2e)
  const float SL = 0.08838834764831845f * 1.4426950408889634f;
  const float ML = 1.4426950408889634e4f;
  const long tb = (long)(b * 16 + h) * 32;
  unsigned short* pw1 = pls + wave * 2048;
  unsigned short* pw2 = pw1 + 1024;

  // initial stage of tile 0 into buffer 0
  {
    const unsigned short* k1t = k1p + tb * 4096 + tid * 8;
    const unsigned short* k2t = k2p + tb * 4096 + tid * 8;
    const unsigned short* vtt = vp + tb * 8192 + tid * 8;
    gll16(k1t, k1s + wave * 512);
    gll16(k1t + 2048, k1s + 2048 + wave * 512);
    gll16(k2t, k2s + wave * 512);
    gll16(k2t + 2048, k2s + 2048 + wave * 512);
#pragma unroll
    for (int rr = 0; rr < 4; rr++)
      gll16(vtt + rr * 2048, vts + rr * 2048 + wave * 512);
  }

  for (int t = 0; t < 32; t++) {
    const int cb = t & 1;
    __syncthreads();  // drains vmcnt: tile t staged; buffer cb^1 free
    if (t < 31) {     // prefetch tile t+1 into other buffer
      const unsigned short* k1t = k1p + (tb + t + 1) * 4096 + tid * 8;
      const unsigned short* k2t = k2p + (tb + t + 1) * 4096 + tid * 8;
      const unsigned short* vtt = vp + (tb + t + 1) * 8192 + tid * 8;
      unsigned short* d1 = k1s + (cb ^ 1) * 4096 + wave * 512;
      unsigned short* d2 = k2s + (cb ^ 1) * 4096 + wave * 512;
      unsigned short* dv = vts + (cb ^ 1) * 8192 + wave * 512;
      gll16(k1t, d1);
      gll16(k1t + 2048, d1 + 2048);
      gll16(k2t, d2);
      gll16(k2t + 2048, d2 + 2048);
#pragma unroll
      for (int rr = 0; rr < 4; rr++)
        gll16(vtt + rr * 2048, dv + rr * 2048);
    }
    float4 mq[4];
#pragma unroll
    for (int nt = 0; nt < 4; nt++)
      mq[nt] = *(const float4*)(mask + (long)b * 2048 + t * 64 + nt * 16 + quad * 4);

    // S^T = K . Q^T : C row = k (quad*4+r), col = q (l15)
    f32x4 s1[4] = {}, s2[4] = {};
#pragma unroll
    for (int nt = 0; nt < 4; nt++) {
      const int row = cb * 4096 + (nt * 16 + l15) * 64;
#pragma unroll
      for (int ks = 0; ks < 2; ks++) {
        const int p = ((ks * 4 + quad) ^ sw) * 8;
        bf16x8 kf1 = *(const bf16x8*)&k1s[row + p];
        bf16x8 kf2 = *(const bf16x8*)&k2s[row + p];
        s1[nt] = __builtin_amdgcn_mfma_f32_16x16x32_bf16(kf1, aq1[ks], s1[nt], 0, 0, 0);
        s2[nt] = __builtin_amdgcn_mfma_f32_16x16x32_bf16(kf2, aq2[ks], s2[nt], 0, 0, 0);
      }
    }
    // scale + mask (log2e domain); per-q-row stats live in 16-lane columns
    float tm1 = -INFINITY, tm2 = -INFINITY;
#pragma unroll
    for (int nt = 0; nt < 4; nt++)
#pragma unroll
      for (int r = 0; r < 4; r++) {
        float ma = fmaf(((const float*)&mq[nt])[r], ML, -ML);  // (1-m)*-1e4*log2e
        s1[nt][r] = fmaf(s1[nt][r], SL, ma);
        s2[nt][r] = fmaf(s2[nt][r], SL, ma);
        tm1 = fmaxf(tm1, s1[nt][r]);
        tm2 = fmaxf(tm2, s2[nt][r]);
      }
    tm1 = fmaxf(tm1, __shfl_xor(tm1, 16, 64)); tm1 = fmaxf(tm1, __shfl_xor(tm1, 32, 64));
    tm2 = fmaxf(tm2, __shfl_xor(tm2, 16, 64)); tm2 = fmaxf(tm2, __shfl_xor(tm2, 32, 64));
    float mn1 = fmaxf(m1, tm1), mn2 = fmaxf(m2, tm2);
    float al1 = exp2f(m1 - mn1), al2 = exp2f(m2 - mn2);
    m1 = mn1; m2 = mn2;
    float rs1 = 0.f, rs2 = 0.f;
#pragma unroll
    for (int nt = 0; nt < 4; nt++)
#pragma unroll
      for (int r = 0; r < 4; r++) {
        float p1 = exp2f(s1[nt][r] - m1);
        float p2 = exp2f(s2[nt][r] - m2);
        s1[nt][r] = p1; s2[nt][r] = p2;
        rs1 += p1; rs2 += p2;
      }
    rs1 += __shfl_xor(rs1, 16, 64); rs1 += __shfl_xor(rs1, 32, 64);
    rs2 += __shfl_xor(rs2, 16, 64); rs2 += __shfl_xor(rs2, 32, 64);
    l1 = l1 * al1 + rs1; l2 = l2 * al2 + rs2;
    if (__any(al1 != 1.f || al2 != 1.f)) {  // rescale only when the max moved
#pragma unroll
      for (int dn = 0; dn < 8; dn++)
#pragma unroll
        for (int r = 0; r < 4; r++) { o1[dn][r] *= al1; o2[dn][r] *= al2; }
    }
    // P^T C-layout -> LDS (wave-private, XOR-swizzled [q=16][k=64])
#pragma unroll
    for (int nt = 0; nt < 4; nt++)
#pragma unroll
      for (int j = 0; j < 2; j++) {
        int k0 = nt * 16 + quad * 4 + j * 2;
        int addr = l15 * 64 + ((k0 >> 3) ^ sw) * 8 + (k0 & 7);
        *(unsigned int*)&pw1[addr] = pack2bf_rn(s1[nt][j * 2], s1[nt][j * 2 + 1]);
        *(unsigned int*)&pw2[addr] = pack2bf_rn(s2[nt][j * 2], s2[nt][j * 2 + 1]);
      }
    asm volatile("s_waitcnt lgkmcnt(0)" ::: "memory");
    // PV: O^T += V^T . P^T  (A = V frag from LDS, shared by both streams)
#pragma unroll
    for (int c = 0; c < 2; c++) {
      const int pp = ((c * 4 + quad) ^ sw) * 8;
      bf16x8 f1 = *(const bf16x8*)&pw1[l15 * 64 + pp];
      bf16x8 f2 = *(const bf16x8*)&pw2[l15 * 64 + pp];
#pragma unroll
      for (int dn = 0; dn < 8; dn++) {
        bf16x8 vf = *(const bf16x8*)&vts[cb * 8192 + (dn * 16 + l15) * 64 + pp];
        o1[dn] = __builtin_amdgcn_mfma_f32_16x16x32_bf16(vf, f1, o1[dn], 0, 0, 0);
        o2[dn] = __builtin_amdgcn_mfma_f32_16x16x32_bf16(vf, f2, o2[dn], 0, 0, 0);
      }
    }
  }
  // epilogue: out = O1/l1 - lam*O2/l2 ; O^T: row d = dn*16+quad*4+r, col q = l15
  float lam = lamp[0];
  float i1 = 1.f / l1, i2 = lam / l2;
  unsigned short* orow = out + (rowq + wave * 16 + l15) * 2048 + h * 128 + quad * 4;
#pragma unroll
  for (int dn = 0; dn < 8; dn++) {
    uint2 st;
    st.x = pack2bf_rn(o1[dn][0] * i1 - o2[dn][0] * i2, o1[dn][1] * i1 - o2[dn][1] * i2);
    st.y = pack2bf_rn(o1[dn][2] * i1 - o2[dn][2] * i2, o1[dn][3] * i1 - o2[dn][3] * i2);
    *(uint2*)(orow + dn * 16) = st;
  }
}

extern "C" void kernel_launch(void* const* d_in, const int* in_sizes, int n_in,
                              void* d_out, int out_size, void* d_ws, size_t ws_size,
                              hipStream_t stream) {
  (void)in_sizes; (void)n_in; (void)out_size; (void)ws_size;
  const float* hs   = (const float*)d_in[0];
  const float* mask = (const float*)d_in[1];
  const float* Wa   = (const float*)d_in[2];
  const float* ba   = (const float*)d_in[3];
  const float* Wp   = (const float*)d_in[4];
  const float* bp   = (const float*)d_in[5];
  const float* lam  = (const float*)d_in[6];
  float* out = (float*)d_out;
  unsigned short* ws = (unsigned short*)d_ws;

  // workspace layout (bf16 elems), total exactly 67,108,864 = 128 MiB
  unsigned short* hsb = ws;                                  // [4096][2048]  (aliased by att)
  unsigned short* WtA = hsb + (long)4096 * 2048;             // [6144][2048]  (aliased by Vt)
  unsigned short* WtP = WtA + (long)6144 * 2048;             // [2048][2048]
  unsigned short* qkv = WtP + (long)2048 * 2048;             // [4096][6144]
  unsigned short* K1p = qkv + (long)4096 * 6144;             // 2*16*32 tiles * 4096
  unsigned short* K2p = K1p + (long)2 * 16 * 2048 * 64;
  unsigned short* Vp  = K2p + (long)2 * 16 * 2048 * 64;      // 2*16*32 tiles * 8192
  unsigned short* Vt  = WtA;                                 // alias (WtA dead after step 4)
  unsigned short* att = hsb;                                 // alias (hsb dead after step 4)

  // 1) casts / weight transposes
  cvt_bf16_k<<<4096, 256, 0, stream>>>(hs, hsb, (long)4096 * 2048);
  cvt_transpose_k<<<dim3(192, 64), 256, 0, stream>>>(Wa, WtA, 6144, 2048);
  cvt_transpose_k<<<dim3(64, 64), 256, 0, stream>>>(Wp, WtP, 2048, 2048);
  // 2) qkv = hs @ W_attn + b_attn (bf16 out)
  gemm_bt<unsigned short><<<dim3(48, 32), 256, 0, stream>>>(hsb, WtA, ba, qkv, 2048, 6144);
  // 3) V transpose + per-head packs (swizzled LDS images)
  transpose_k<<<dim3(64, 64, 2), 256, 0, stream>>>(
      qkv + 4096, Vt, 6144, 2048, (long)2048 * 6144, (long)2048 * 2048);
  vpack_k<<<dim3(32, 16, 2), 256, 0, stream>>>(Vt, Vp);
  kpack_k<<<dim3(32, 16, 2), 256, 0, stream>>>(qkv, K1p, K2p);
  // 4) differential flash attention
  attn_k<<<dim3(32, 16, 2), 256, 0, stream>>>(qkv, K1p, K2p, Vp, mask, lam, att);
  // 5) out = att @ W_proj + b_proj (f32 out)
  gemm_bt<float><<<dim3(16, 32), 256, 0, stream>>>(att, WtP, bp, out, 2048, 2048);
}

// Round 5
// 503.676 us; speedup vs baseline: 1.7961x; 1.0978x over previous
//
#include <hip/hip_runtime.h>
#include <hip/hip_bf16.h>

typedef __attribute__((ext_vector_type(8))) short bf16x8;
typedef __attribute__((ext_vector_type(8))) unsigned short u16x8;
typedef __attribute__((ext_vector_type(4))) float f32x4;

__device__ __forceinline__ unsigned short f2bf(float f) {
  union { float f; unsigned int i; } v; v.f = f;
  unsigned int r = v.i + 0x7FFFu + ((v.i >> 16) & 1u);  // RNE
  return (unsigned short)(r >> 16);
}
// fast round-to-nearest (ties-away) pack of two f32 -> packed bf16x2
__device__ __forceinline__ unsigned int pack2bf_rn(float a, float b) {
  union { float f; unsigned int i; } x, y; x.f = a; y.f = b;
  return ((x.i + 0x8000u) >> 16) | ((y.i + 0x8000u) & 0xFFFF0000u);
}
// async global->LDS, 16B per lane; LDS dest = wave-uniform base + lane*16
__device__ __forceinline__ void gll16(const unsigned short* g, unsigned short* l) {
  __builtin_amdgcn_global_load_lds(
      (const __attribute__((address_space(1))) unsigned int*)g,
      (__attribute__((address_space(3))) unsigned int*)l, 16, 0, 0);
}

// ---------------- f32 -> bf16 straight cast ----------------
__global__ void cvt_bf16_k(const float* __restrict__ in, unsigned short* __restrict__ out,
                           long n) {
  long i = ((long)blockIdx.x * 256 + threadIdx.x) * 8;
  if (i + 8 > n) return;
  float4 a = *(const float4*)(in + i);
  float4 b = *(const float4*)(in + i + 4);
  u16x8 o;
  o[0] = f2bf(a.x); o[1] = f2bf(a.y); o[2] = f2bf(a.z); o[3] = f2bf(a.w);
  o[4] = f2bf(b.x); o[5] = f2bf(b.y); o[6] = f2bf(b.z); o[7] = f2bf(b.w);
  *(u16x8*)(out + i) = o;
}

// ---------------- f32 in -> bf16 out, transposed ----------------
__global__ void cvt_transpose_k(const float* __restrict__ in, unsigned short* __restrict__ out,
                                long in_rs, long out_rs) {
  __shared__ unsigned short tile[32][33];
  int c0 = blockIdx.x * 32, r0 = blockIdx.y * 32;
  int tx = threadIdx.x & 31, ty = threadIdx.x >> 5;
#pragma unroll
  for (int i = 0; i < 32; i += 8)
    tile[ty + i][tx] = f2bf(in[(long)(r0 + ty + i) * in_rs + c0 + tx]);
  __syncthreads();
#pragma unroll
  for (int i = 0; i < 32; i += 8)
    out[(long)(c0 + ty + i) * out_rs + r0 + tx] = tile[tx][ty + i];
}

// ---------------- bf16 transpose ----------------
__global__ void transpose_k(const unsigned short* __restrict__ in,
                            unsigned short* __restrict__ out,
                            long in_rs, long out_rs, long in_zoff, long out_zoff) {
  __shared__ unsigned short tile[32][33];
  const unsigned short* ip = in + (long)blockIdx.z * in_zoff;
  unsigned short* op = out + (long)blockIdx.z * out_zoff;
  int c0 = blockIdx.x * 32, r0 = blockIdx.y * 32;
  int tx = threadIdx.x & 31, ty = threadIdx.x >> 5;
#pragma unroll
  for (int i = 0; i < 32; i += 8)
    tile[ty + i][tx] = ip[(long)(r0 + ty + i) * in_rs + c0 + tx];
  __syncthreads();
#pragma unroll
  for (int i = 0; i < 32; i += 8)
    op[(long)(c0 + ty + i) * out_rs + r0 + tx] = tile[tx][ty + i];
}

// ---- pack V^T per (b,h) into tile-major, LDS-image XOR-swizzled layout ----
__global__ void vpack_k(const unsigned short* __restrict__ vt, unsigned short* __restrict__ vp) {
  const int t = blockIdx.x, h = blockIdx.y, b = blockIdx.z, tid = threadIdx.x;
  const int d = tid >> 1;
  const long tile = ((long)(b * 16 + h) * 32 + t) * 8192;
  const unsigned short* src = vt + ((long)b * 2048 + h * 128 + d) * 2048 + t * 64;
#pragma unroll
  for (int i = 0; i < 4; i++) {
    int cc = (tid & 1) * 4 + i;
    u16x8 v = *(const u16x8*)(src + cc * 8);
    *(u16x8*)(vp + tile + d * 64 + ((cc ^ (d & 7)) * 8)) = v;
  }
}

// ---- pack K1/K2 per (b,h) tiles, swizzled: chunk c of row s stored at c^(s&7) ----
__global__ void kpack_k(const unsigned short* __restrict__ qkv,
                        unsigned short* __restrict__ k1p, unsigned short* __restrict__ k2p) {
  const int t = blockIdx.x, h = blockIdx.y, b = blockIdx.z, tid = threadIdx.x;
  const long tile = ((long)(b * 16 + h) * 32 + t) * 4096;
#pragma unroll
  for (int rd = 0; rd < 2; rd++) {
    int row = rd * 32 + (tid >> 3);
    int c = tid & 7;
    const unsigned short* src = qkv + ((long)b * 2048 + t * 64 + row) * 6144 + h * 64 + c * 8;
    long dst = tile + row * 64 + ((c ^ (row & 7)) * 8);
    *(u16x8*)(k1p + dst) = *(const u16x8*)(src + 2048);
    *(u16x8*)(k2p + dst) = *(const u16x8*)(src + 3072);
  }
}

// ---------- GEMM (m97 structure): C = A . Bt^T + bias, bf16 in, f32 acc ----------
template <typename OT>
__global__ __launch_bounds__(256) void gemm_bt(
    const unsigned short* __restrict__ A,   // [M][K]
    const unsigned short* __restrict__ Bt,  // [N][K]
    const float* __restrict__ bias,         // [N]
    OT* __restrict__ C, int K, int ldc) {
  __shared__ unsigned short As[128 * 32];
  __shared__ unsigned short Bs[128 * 32];
  const int m0 = blockIdx.y * 128, n0 = blockIdx.x * 128;
  const int tid = threadIdx.x, lane = tid & 63, wave = tid >> 6;
  const int wm = (wave >> 1) * 64, wn = (wave & 1) * 64;
  const int quad = lane >> 4, l15 = lane & 15;
  const int ar = tid >> 2, ak = (tid & 3) * 8;

  f32x4 acc[4][4] = {};
  const unsigned short* Ap = A + (long)(m0 + ar) * K + ak;
  const unsigned short* Bp = Bt + (long)(n0 + ar) * K + ak;
  unsigned short* AsW = As + wave * 512;
  unsigned short* BsW = Bs + wave * 512;

  for (int kb = 0; kb < K; kb += 32) {
    __syncthreads();
    gll16(Ap + kb, AsW);
    gll16(Ap + (long)64 * K + kb, AsW + 2048);
    gll16(Bp + kb, BsW);
    gll16(Bp + (long)64 * K + kb, BsW + 2048);
    __syncthreads();
    bf16x8 af[4], bfr[4];
#pragma unroll
    for (int t = 0; t < 4; t++)
      af[t] = *(const bf16x8*)&As[(wm + t * 16 + l15) * 32 + quad * 8];
#pragma unroll
    for (int t = 0; t < 4; t++)
      bfr[t] = *(const bf16x8*)&Bs[(wn + t * 16 + l15) * 32 + quad * 8];
#pragma unroll
    for (int i = 0; i < 4; i++)
#pragma unroll
      for (int j = 0; j < 4; j++)
        acc[i][j] = __builtin_amdgcn_mfma_f32_16x16x32_bf16(af[i], bfr[j], acc[i][j], 0, 0, 0);
  }
#pragma unroll
  for (int j = 0; j < 4; j++) {
    int n = n0 + wn + j * 16 + l15;
    float bv = bias[n];
#pragma unroll
    for (int i = 0; i < 4; i++) {
      int mr = m0 + wm + i * 16 + quad * 4;
#pragma unroll
      for (int r = 0; r < 4; r++) {
        float v = acc[i][j][r] + bv;
        if constexpr (sizeof(OT) == 2)
          C[(long)(mr + r) * ldc + n] = f2bf(v);
        else
          C[(long)(mr + r) * ldc + n] = v;
      }
    }
  }
}

// ------- differential flash attention (S^T form, fixed-max, q32/wave, dbuf) -------
// grid (16,16,2), block 256. Wave w owns q rows [w*32, w*32+32) (2 q-tiles).
__global__ __launch_bounds__(256, 2) void attn_k(
    const unsigned short* __restrict__ qkv,  // [B*S][6144] (q|k|v) bf16
    const unsigned short* __restrict__ k1p,  // packed swizzled tiles
    const unsigned short* __restrict__ k2p,
    const unsigned short* __restrict__ vp,
    const float* __restrict__ mask,          // [B][S] f32
    const float* __restrict__ lamp,          // [1] f32
    unsigned short* __restrict__ out) {      // [B*S][2048] bf16
  __shared__ unsigned short k1s[2 * 4096];
  __shared__ unsigned short k2s[2 * 4096];
  __shared__ unsigned short vts[2 * 8192];
  __shared__ unsigned short pls[4 * 2048];  // [wave][qt*2+st][q16][k32 swizzled]
  const int b = blockIdx.z, h = blockIdx.y, q0 = blockIdx.x * 128;
  const int tid = threadIdx.x, lane = tid & 63, wave = tid >> 6;
  const int quad = lane >> 4, l15 = lane & 15;
  const long rowq = (long)b * 2048 + q0;
  const int sw = l15 & 7;
  const int psw = l15 & 3;

  // Q fragments (B-operand layout), 2 q-tiles per wave, straight from global
  bf16x8 aq1[2][2], aq2[2][2];
#pragma unroll
  for (int qt = 0; qt < 2; qt++) {
    const unsigned short* qr =
        qkv + (rowq + wave * 32 + qt * 16 + l15) * 6144 + h * 64 + quad * 8;
    aq1[qt][0] = *(const bf16x8*)qr;
    aq1[qt][1] = *(const bf16x8*)(qr + 32);
    aq2[qt][0] = *(const bf16x8*)(qr + 1024);
    aq2[qt][1] = *(const bf16x8*)(qr + 1056);
  }
  f32x4 o1[2][8] = {}, o2[2][8] = {};
  float lp1[2] = {0.f, 0.f}, lp2[2] = {0.f, 0.f};
  // log2e-scaled domain, fixed max 0: p = exp2(s*SL + (1-m)*(-1e4*log2e))
  const float SL = 0.08838834764831845f * 1.4426950408889634f;
  const float ML = 1.4426950408889634e4f;
  const long tb = (long)(b * 16 + h) * 32;
  unsigned short* pw = pls + wave * 2048;

  // initial stage of tile 0 into buffer 0
  {
    const unsigned short* k1t = k1p + tb * 4096 + tid * 8;
    const unsigned short* k2t = k2p + tb * 4096 + tid * 8;
    const unsigned short* vtt = vp + tb * 8192 + tid * 8;
    gll16(k1t, k1s + wave * 512);
    gll16(k1t + 2048, k1s + 2048 + wave * 512);
    gll16(k2t, k2s + wave * 512);
    gll16(k2t + 2048, k2s + 2048 + wave * 512);
#pragma unroll
    for (int rr = 0; rr < 4; rr++)
      gll16(vtt + rr * 2048, vts + rr * 2048 + wave * 512);
  }

  for (int t = 0; t < 32; t++) {
    const int cb = t & 1;
    __syncthreads();  // drains vmcnt: tile t staged; buffer cb^1 free
    if (t < 31) {     // prefetch tile t+1 into other buffer
      const unsigned short* k1t = k1p + (tb + t + 1) * 4096 + tid * 8;
      const unsigned short* k2t = k2p + (tb + t + 1) * 4096 + tid * 8;
      const unsigned short* vtt = vp + (tb + t + 1) * 8192 + tid * 8;
      unsigned short* d1 = k1s + (cb ^ 1) * 4096 + wave * 512;
      unsigned short* d2 = k2s + (cb ^ 1) * 4096 + wave * 512;
      unsigned short* dv = vts + (cb ^ 1) * 8192 + wave * 512;
      gll16(k1t, d1);
      gll16(k1t + 2048, d1 + 2048);
      gll16(k2t, d2);
      gll16(k2t + 2048, d2 + 2048);
#pragma unroll
      for (int rr = 0; rr < 4; rr++)
        gll16(vtt + rr * 2048, dv + rr * 2048);
    }
    float4 mq[4];
#pragma unroll
    for (int nt = 0; nt < 4; nt++)
      mq[nt] = *(const float4*)(mask + (long)b * 2048 + t * 64 + nt * 16 + quad * 4);

#pragma unroll
    for (int half = 0; half < 2; half++) {
      // S^T = K . Q^T for k-half (32 k rows): C row=k (quad*4+r), col=q (l15)
      f32x4 s1[2][2] = {}, s2[2][2] = {};
#pragma unroll
      for (int np = 0; np < 2; np++) {
        const int row = cb * 4096 + (half * 32 + np * 16 + l15) * 64;
#pragma unroll
        for (int ks = 0; ks < 2; ks++) {
          const int p = ((ks * 4 + quad) ^ sw) * 8;
          bf16x8 kf1 = *(const bf16x8*)&k1s[row + p];
          bf16x8 kf2 = *(const bf16x8*)&k2s[row + p];
#pragma unroll
          for (int qt = 0; qt < 2; qt++) {
            s1[qt][np] = __builtin_amdgcn_mfma_f32_16x16x32_bf16(kf1, aq1[qt][ks], s1[qt][np], 0, 0, 0);
            s2[qt][np] = __builtin_amdgcn_mfma_f32_16x16x32_bf16(kf2, aq2[qt][ks], s2[qt][np], 0, 0, 0);
          }
        }
      }
      // fixed-max softmax: p = exp2(s*SL + ma); accumulate per-lane partial l
      float ma[2][4];
#pragma unroll
      for (int np = 0; np < 2; np++)
#pragma unroll
        for (int r = 0; r < 4; r++)
          ma[np][r] = fmaf(((const float*)&mq[half * 2 + np])[r], ML, -ML);
#pragma unroll
      for (int qt = 0; qt < 2; qt++)
#pragma unroll
        for (int np = 0; np < 2; np++) {
#pragma unroll
          for (int r = 0; r < 4; r++) {
            float p1 = exp2f(fmaf(s1[qt][np][r], SL, ma[np][r]));
            float p2 = exp2f(fmaf(s2[qt][np][r], SL, ma[np][r]));
            lp1[qt] += p1; lp2[qt] += p2;
            s1[qt][np][r] = p1; s2[qt][np][r] = p2;
          }
          // write b64: k0 = np*16+quad*4, chunk = k0>>3, pos = chunk^psw
          const int chunk = np * 2 + (quad >> 1);
          const int addr = l15 * 32 + ((chunk ^ psw) * 8) + (quad & 1) * 4;
          uint2 w1, w2;
          w1.x = pack2bf_rn(s1[qt][np][0], s1[qt][np][1]);
          w1.y = pack2bf_rn(s1[qt][np][2], s1[qt][np][3]);
          w2.x = pack2bf_rn(s2[qt][np][0], s2[qt][np][1]);
          w2.y = pack2bf_rn(s2[qt][np][2], s2[qt][np][3]);
          *(uint2*)&pw[(qt * 2 + 0) * 512 + addr] = w1;
          *(uint2*)&pw[(qt * 2 + 1) * 512 + addr] = w2;
        }
      asm volatile("s_waitcnt lgkmcnt(0)" ::: "memory");
      // PV for this k-half: O^T += V^T . P^T  (V frag shared by 2qt x 2streams)
      bf16x8 f1[2], f2[2];
      {
        const int raddr = l15 * 32 + ((quad ^ psw) * 8);
#pragma unroll
        for (int qt = 0; qt < 2; qt++) {
          f1[qt] = *(const bf16x8*)&pw[(qt * 2 + 0) * 512 + raddr];
          f2[qt] = *(const bf16x8*)&pw[(qt * 2 + 1) * 512 + raddr];
        }
      }
#pragma unroll
      for (int dn = 0; dn < 8; dn++) {
        const int pp = ((half * 4 + quad) ^ sw) * 8;
        bf16x8 vf = *(const bf16x8*)&vts[cb * 8192 + (dn * 16 + l15) * 64 + pp];
#pragma unroll
        for (int qt = 0; qt < 2; qt++) {
          o1[qt][dn] = __builtin_amdgcn_mfma_f32_16x16x32_bf16(vf, f1[qt], o1[qt][dn], 0, 0, 0);
          o2[qt][dn] = __builtin_amdgcn_mfma_f32_16x16x32_bf16(vf, f2[qt], o2[qt][dn], 0, 0, 0);
        }
      }
      asm volatile("s_waitcnt lgkmcnt(0)" ::: "memory");  // pls reused next half
    }
  }
  // epilogue: reduce l across quads, out = O1/l1 - lam*O2/l2
  float lam = lamp[0];
#pragma unroll
  for (int qt = 0; qt < 2; qt++) {
    float l1 = lp1[qt], l2 = lp2[qt];
    l1 += __shfl_xor(l1, 16, 64); l1 += __shfl_xor(l1, 32, 64);
    l2 += __shfl_xor(l2, 16, 64); l2 += __shfl_xor(l2, 32, 64);
    float i1 = 1.f / l1, i2 = lam / l2;
    unsigned short* orow =
        out + (rowq + wave * 32 + qt * 16 + l15) * 2048 + h * 128 + quad * 4;
#pragma unroll
    for (int dn = 0; dn < 8; dn++) {
      uint2 st;
      st.x = pack2bf_rn(o1[qt][dn][0] * i1 - o2[qt][dn][0] * i2,
                        o1[qt][dn][1] * i1 - o2[qt][dn][1] * i2);
      st.y = pack2bf_rn(o1[qt][dn][2] * i1 - o2[qt][dn][2] * i2,
                        o1[qt][dn][3] * i1 - o2[qt][dn][3] * i2);
      *(uint2*)(orow + dn * 16) = st;
    }
  }
}

extern "C" void kernel_launch(void* const* d_in, const int* in_sizes, int n_in,
                              void* d_out, int out_size, void* d_ws, size_t ws_size,
                              hipStream_t stream) {
  (void)in_sizes; (void)n_in; (void)out_size; (void)ws_size;
  const float* hs   = (const float*)d_in[0];
  const float* mask = (const float*)d_in[1];
  const float* Wa   = (const float*)d_in[2];
  const float* ba   = (const float*)d_in[3];
  const float* Wp   = (const float*)d_in[4];
  const float* bp   = (const float*)d_in[5];
  const float* lam  = (const float*)d_in[6];
  float* out = (float*)d_out;
  unsigned short* ws = (unsigned short*)d_ws;

  // workspace layout (bf16 elems), total exactly 67,108,864 = 128 MiB
  unsigned short* hsb = ws;                                  // [4096][2048]  (aliased by att)
  unsigned short* WtA = hsb + (long)4096 * 2048;             // [6144][2048]  (aliased by Vt)
  unsigned short* WtP = WtA + (long)6144 * 2048;             // [2048][2048]
  unsigned short* qkv = WtP + (long)2048 * 2048;             // [4096][6144]
  unsigned short* K1p = qkv + (long)4096 * 6144;             // 2*16*32 tiles * 4096
  unsigned short* K2p = K1p + (long)2 * 16 * 2048 * 64;
  unsigned short* Vp  = K2p + (long)2 * 16 * 2048 * 64;      // 2*16*32 tiles * 8192
  unsigned short* Vt  = WtA;                                 // alias (WtA dead after step 4)
  unsigned short* att = hsb;                                 // alias (hsb dead after step 4)

  // 1) casts / weight transposes
  cvt_bf16_k<<<4096, 256, 0, stream>>>(hs, hsb, (long)4096 * 2048);
  cvt_transpose_k<<<dim3(192, 64), 256, 0, stream>>>(Wa, WtA, 6144, 2048);
  cvt_transpose_k<<<dim3(64, 64), 256, 0, stream>>>(Wp, WtP, 2048, 2048);
  // 2) qkv = hs @ W_attn + b_attn (bf16 out)
  gemm_bt<unsigned short><<<dim3(48, 32), 256, 0, stream>>>(hsb, WtA, ba, qkv, 2048, 6144);
  // 3) V transpose + per-head packs (swizzled LDS images)
  transpose_k<<<dim3(64, 64, 2), 256, 0, stream>>>(
      qkv + 4096, Vt, 6144, 2048, (long)2048 * 6144, (long)2048 * 2048);
  vpack_k<<<dim3(32, 16, 2), 256, 0, stream>>>(Vt, Vp);
  kpack_k<<<dim3(32, 16, 2), 256, 0, stream>>>(qkv, K1p, K2p);
  // 4) differential flash attention (q-tile 128)
  attn_k<<<dim3(16, 16, 2), 256, 0, stream>>>(qkv, K1p, K2p, Vp, mask, lam, att);
  // 5) out = att @ W_proj + b_proj (f32 out)
  gemm_bt<float><<<dim3(16, 32), 256, 0, stream>>>(att, WtP, bp, out, 2048, 2048);
}

// Round 6
// 496.341 us; speedup vs baseline: 1.8227x; 1.0148x over previous
//
#include <hip/hip_runtime.h>
#include <hip/hip_bf16.h>

typedef __attribute__((ext_vector_type(8))) short bf16x8;
typedef __attribute__((ext_vector_type(8))) unsigned short u16x8;
typedef __attribute__((ext_vector_type(4))) float f32x4;

__device__ __forceinline__ unsigned short f2bf(float f) {
  union { float f; unsigned int i; } v; v.f = f;
  unsigned int r = v.i + 0x7FFFu + ((v.i >> 16) & 1u);  // RNE
  return (unsigned short)(r >> 16);
}
// fast round-to-nearest (ties-away) pack of two f32 -> packed bf16x2
__device__ __forceinline__ unsigned int pack2bf_rn(float a, float b) {
  union { float f; unsigned int i; } x, y; x.f = a; y.f = b;
  return ((x.i + 0x8000u) >> 16) | ((y.i + 0x8000u) & 0xFFFF0000u);
}
// async global->LDS, 16B per lane; LDS dest = wave-uniform base + lane*16
__device__ __forceinline__ void gll16(const unsigned short* g, unsigned short* l) {
  __builtin_amdgcn_global_load_lds(
      (const __attribute__((address_space(1))) unsigned int*)g,
      (__attribute__((address_space(3))) unsigned int*)l, 16, 0, 0);
}

// ---------------- f32 -> bf16 straight cast ----------------
__global__ void cvt_bf16_k(const float* __restrict__ in, unsigned short* __restrict__ out,
                           long n) {
  long i = ((long)blockIdx.x * 256 + threadIdx.x) * 8;
  if (i + 8 > n) return;
  float4 a = *(const float4*)(in + i);
  float4 b = *(const float4*)(in + i + 4);
  u16x8 o;
  o[0] = f2bf(a.x); o[1] = f2bf(a.y); o[2] = f2bf(a.z); o[3] = f2bf(a.w);
  o[4] = f2bf(b.x); o[5] = f2bf(b.y); o[6] = f2bf(b.z); o[7] = f2bf(b.w);
  *(u16x8*)(out + i) = o;
}

// ---------------- f32 in -> bf16 out, transposed ----------------
__global__ void cvt_transpose_k(const float* __restrict__ in, unsigned short* __restrict__ out,
                                long in_rs, long out_rs) {
  __shared__ unsigned short tile[32][33];
  int c0 = blockIdx.x * 32, r0 = blockIdx.y * 32;
  int tx = threadIdx.x & 31, ty = threadIdx.x >> 5;
#pragma unroll
  for (int i = 0; i < 32; i += 8)
    tile[ty + i][tx] = f2bf(in[(long)(r0 + ty + i) * in_rs + c0 + tx]);
  __syncthreads();
#pragma unroll
  for (int i = 0; i < 32; i += 8)
    out[(long)(c0 + ty + i) * out_rs + r0 + tx] = tile[tx][ty + i];
}

// ---- qkv GEMM with fused scatter epilogue ----
// C = A . Bt^T + bias over N=6144. n-region: [0,2048) -> qQ row-major,
// [2048,4096) -> K1p/K2p swizzled tiles, [4096,6144) -> Vp transposed swizzled tiles.
__global__ __launch_bounds__(256) void gemm_qkv(
    const unsigned short* __restrict__ A,   // [4096][2048] bf16
    const unsigned short* __restrict__ Bt,  // [6144][2048] bf16
    const float* __restrict__ bias,         // [6144]
    unsigned short* __restrict__ qQ,        // [4096][2048]
    unsigned short* __restrict__ k1p, unsigned short* __restrict__ k2p,
    unsigned short* __restrict__ vp) {
  const int K = 2048;
  __shared__ unsigned short As[128 * 32];
  __shared__ unsigned short Bs[128 * 32];
  const int m0 = blockIdx.y * 128, n0 = blockIdx.x * 128;
  const int tid = threadIdx.x, lane = tid & 63, wave = tid >> 6;
  const int wm = (wave >> 1) * 64, wn = (wave & 1) * 64;
  const int quad = lane >> 4, l15 = lane & 15;
  const int ar = tid >> 2, ak = (tid & 3) * 8;

  f32x4 acc[4][4] = {};
  const unsigned short* Ap = A + (long)(m0 + ar) * K + ak;
  const unsigned short* Bp = Bt + (long)(n0 + ar) * K + ak;
  unsigned short* AsW = As + wave * 512;
  unsigned short* BsW = Bs + wave * 512;

  for (int kb = 0; kb < K; kb += 32) {
    __syncthreads();
    gll16(Ap + kb, AsW);
    gll16(Ap + (long)64 * K + kb, AsW + 2048);
    gll16(Bp + kb, BsW);
    gll16(Bp + (long)64 * K + kb, BsW + 2048);
    __syncthreads();
    bf16x8 af[4], bfr[4];
#pragma unroll
    for (int t = 0; t < 4; t++)
      af[t] = *(const bf16x8*)&As[(wm + t * 16 + l15) * 32 + quad * 8];
#pragma unroll
    for (int t = 0; t < 4; t++)
      bfr[t] = *(const bf16x8*)&Bs[(wn + t * 16 + l15) * 32 + quad * 8];
#pragma unroll
    for (int i = 0; i < 4; i++)
#pragma unroll
      for (int j = 0; j < 4; j++)
        acc[i][j] = __builtin_amdgcn_mfma_f32_16x16x32_bf16(af[i], bfr[j], acc[i][j], 0, 0, 0);
  }

  const int ncol = n0 + wn;  // wave-uniform 64-col base
  if (ncol < 2048) {
    // ---- Q region: row-major [4096][2048] ----
#pragma unroll
    for (int j = 0; j < 4; j++) {
      int n = ncol + j * 16 + l15;
      float bv = bias[n];
#pragma unroll
      for (int i = 0; i < 4; i++) {
        int mr = m0 + wm + i * 16 + quad * 4;
#pragma unroll
        for (int r = 0; r < 4; r++)
          qQ[(long)(mr + r) * 2048 + n] = f2bf(acc[i][j][r] + bv);
      }
    }
  } else if (ncol < 4096) {
    // ---- K region: kpack layout tile[(b,h,t)][row*64 + (c^(row&7))*8 + e] ----
    unsigned short* kp = (ncol >= 3072) ? k2p : k1p;
#pragma unroll
    for (int j = 0; j < 4; j++) {
      int n = ncol + j * 16 + l15;
      float bv = bias[n];
      int kk = (n - 2048) & 1023;
      int h = kk >> 6, c = (kk >> 3) & 7, e = kk & 7;
#pragma unroll
      for (int i = 0; i < 4; i++) {
        int mr = m0 + wm + i * 16 + quad * 4;
        int b = mr >> 11, s = mr & 2047;
        long tb2 = ((long)(b * 16 + h) * 32 + (s >> 6)) * 4096 + e;
        int row0 = s & 63;
#pragma unroll
        for (int r = 0; r < 4; r++) {
          int row = row0 + r;
          kp[tb2 + row * 64 + ((c ^ (row & 7)) << 3)] = f2bf(acc[i][j][r] + bv);
        }
      }
    }
  } else {
    // ---- V region: vpack layout tile[(b,h,t)][d*64 + (cc^(d&7))*8 + (s&7)] ----
#pragma unroll
    for (int j = 0; j < 4; j++) {
      int n = ncol + j * 16 + l15;
      float bv = bias[n];
      int vv = n - 4096;
      int h = vv >> 7, d = vv & 127;
#pragma unroll
      for (int i = 0; i < 4; i++) {
        int mr = m0 + wm + i * 16 + quad * 4;
        int b = mr >> 11, s = mr & 2047;
        int cc = (s & 63) >> 3;
        long dst = ((long)(b * 16 + h) * 32 + (s >> 6)) * 8192 + d * 64 +
                   ((cc ^ (d & 7)) << 3) + (quad & 1) * 4;
        uint2 st;
        st.x = pack2bf_rn(acc[i][j][0] + bv, acc[i][j][1] + bv);
        st.y = pack2bf_rn(acc[i][j][2] + bv, acc[i][j][3] + bv);
        *(uint2*)&vp[dst] = st;
      }
    }
  }
}

// ---------- GEMM (m97 structure): C = A . Bt^T + bias, f32 out ----------
__global__ __launch_bounds__(256) void gemm_bt_f32(
    const unsigned short* __restrict__ A,   // [M][K]
    const unsigned short* __restrict__ Bt,  // [N][K]
    const float* __restrict__ bias,         // [N]
    float* __restrict__ C, int K, int ldc) {
  __shared__ unsigned short As[128 * 32];
  __shared__ unsigned short Bs[128 * 32];
  const int m0 = blockIdx.y * 128, n0 = blockIdx.x * 128;
  const int tid = threadIdx.x, lane = tid & 63, wave = tid >> 6;
  const int wm = (wave >> 1) * 64, wn = (wave & 1) * 64;
  const int quad = lane >> 4, l15 = lane & 15;
  const int ar = tid >> 2, ak = (tid & 3) * 8;

  f32x4 acc[4][4] = {};
  const unsigned short* Ap = A + (long)(m0 + ar) * K + ak;
  const unsigned short* Bp = Bt + (long)(n0 + ar) * K + ak;
  unsigned short* AsW = As + wave * 512;
  unsigned short* BsW = Bs + wave * 512;

  for (int kb = 0; kb < K; kb += 32) {
    __syncthreads();
    gll16(Ap + kb, AsW);
    gll16(Ap + (long)64 * K + kb, AsW + 2048);
    gll16(Bp + kb, BsW);
    gll16(Bp + (long)64 * K + kb, BsW + 2048);
    __syncthreads();
    bf16x8 af[4], bfr[4];
#pragma unroll
    for (int t = 0; t < 4; t++)
      af[t] = *(const bf16x8*)&As[(wm + t * 16 + l15) * 32 + quad * 8];
#pragma unroll
    for (int t = 0; t < 4; t++)
      bfr[t] = *(const bf16x8*)&Bs[(wn + t * 16 + l15) * 32 + quad * 8];
#pragma unroll
    for (int i = 0; i < 4; i++)
#pragma unroll
      for (int j = 0; j < 4; j++)
        acc[i][j] = __builtin_amdgcn_mfma_f32_16x16x32_bf16(af[i], bfr[j], acc[i][j], 0, 0, 0);
  }
#pragma unroll
  for (int j = 0; j < 4; j++) {
    int n = n0 + wn + j * 16 + l15;
    float bv = bias[n];
#pragma unroll
    for (int i = 0; i < 4; i++) {
      int mr = m0 + wm + i * 16 + quad * 4;
#pragma unroll
      for (int r = 0; r < 4; r++)
        C[(long)(mr + r) * ldc + n] = acc[i][j][r] + bv;
    }
  }
}

// ------- differential flash attention (S^T form, fixed-max, q32/wave, dbuf) -------
// grid (16,16,2), block 256. Wave w owns q rows [w*32, w*32+32) (2 q-tiles).
__global__ __launch_bounds__(256, 2) void attn_k(
    const unsigned short* __restrict__ qQ,   // [B*S][2048] bf16 (q only)
    const unsigned short* __restrict__ k1p,  // packed swizzled tiles
    const unsigned short* __restrict__ k2p,
    const unsigned short* __restrict__ vp,
    const float* __restrict__ mask,          // [B][S] f32
    const float* __restrict__ lamp,          // [1] f32
    unsigned short* __restrict__ out) {      // [B*S][2048] bf16
  __shared__ unsigned short k1s[2 * 4096];
  __shared__ unsigned short k2s[2 * 4096];
  __shared__ unsigned short vts[2 * 8192];
  __shared__ unsigned short pls[4 * 2048];  // [wave][qt*2+st][q16 x k32 swizzled]
  const int b = blockIdx.z, h = blockIdx.y, q0 = blockIdx.x * 128;
  const int tid = threadIdx.x, lane = tid & 63, wave = tid >> 6;
  const int quad = lane >> 4, l15 = lane & 15;
  const long rowq = (long)b * 2048 + q0;
  const int sw = l15 & 7;

  // Q fragments (B-operand layout), 2 q-tiles per wave, straight from global
  bf16x8 aq1[2][2], aq2[2][2];
#pragma unroll
  for (int qt = 0; qt < 2; qt++) {
    const unsigned short* qr =
        qQ + (rowq + wave * 32 + qt * 16 + l15) * 2048 + h * 64 + quad * 8;
    aq1[qt][0] = *(const bf16x8*)qr;
    aq1[qt][1] = *(const bf16x8*)(qr + 32);
    aq2[qt][0] = *(const bf16x8*)(qr + 1024);
    aq2[qt][1] = *(const bf16x8*)(qr + 1056);
  }
  f32x4 o1[2][8] = {}, o2[2][8] = {};
  float lp1[2] = {0.f, 0.f}, lp2[2] = {0.f, 0.f};
  // log2e-scaled domain, fixed max 0: p = exp2(s*SL + (1-m)*(-1e4*log2e))
  const float SL = 0.08838834764831845f * 1.4426950408889634f;
  const float ML = 1.4426950408889634e4f;
  const long tb = (long)(b * 16 + h) * 32;
  unsigned short* pw = pls + wave * 2048;

  // initial stage of tile 0 into buffer 0
  {
    const unsigned short* k1t = k1p + tb * 4096 + tid * 8;
    const unsigned short* k2t = k2p + tb * 4096 + tid * 8;
    const unsigned short* vtt = vp + tb * 8192 + tid * 8;
    gll16(k1t, k1s + wave * 512);
    gll16(k1t + 2048, k1s + 2048 + wave * 512);
    gll16(k2t, k2s + wave * 512);
    gll16(k2t + 2048, k2s + 2048 + wave * 512);
#pragma unroll
    for (int rr = 0; rr < 4; rr++)
      gll16(vtt + rr * 2048, vts + rr * 2048 + wave * 512);
  }

  for (int t = 0; t < 32; t++) {
    const int cb = t & 1;
    __syncthreads();  // drains vmcnt: tile t staged; buffer cb^1 free
    if (t < 31) {     // prefetch tile t+1 into other buffer
      const unsigned short* k1t = k1p + (tb + t + 1) * 4096 + tid * 8;
      const unsigned short* k2t = k2p + (tb + t + 1) * 4096 + tid * 8;
      const unsigned short* vtt = vp + (tb + t + 1) * 8192 + tid * 8;
      unsigned short* d1 = k1s + (cb ^ 1) * 4096 + wave * 512;
      unsigned short* d2 = k2s + (cb ^ 1) * 4096 + wave * 512;
      unsigned short* dv = vts + (cb ^ 1) * 8192 + wave * 512;
      gll16(k1t, d1);
      gll16(k1t + 2048, d1 + 2048);
      gll16(k2t, d2);
      gll16(k2t + 2048, d2 + 2048);
#pragma unroll
      for (int rr = 0; rr < 4; rr++)
        gll16(vtt + rr * 2048, dv + rr * 2048);
    }
    float4 mq[4];
#pragma unroll
    for (int nt = 0; nt < 4; nt++)
      mq[nt] = *(const float4*)(mask + (long)b * 2048 + t * 64 + nt * 16 + quad * 4);

#pragma unroll
    for (int half = 0; half < 2; half++) {
      // S^T = K . Q^T for k-half (32 k rows): C row=k (quad*4+r), col=q (l15)
      f32x4 s1[2][2] = {}, s2[2][2] = {};
#pragma unroll
      for (int np = 0; np < 2; np++) {
        const int row = cb * 4096 + (half * 32 + np * 16 + l15) * 64;
#pragma unroll
        for (int ks = 0; ks < 2; ks++) {
          const int p = ((ks * 4 + quad) ^ sw) * 8;
          bf16x8 kf1 = *(const bf16x8*)&k1s[row + p];
          bf16x8 kf2 = *(const bf16x8*)&k2s[row + p];
#pragma unroll
          for (int qt = 0; qt < 2; qt++) {
            s1[qt][np] = __builtin_amdgcn_mfma_f32_16x16x32_bf16(kf1, aq1[qt][ks], s1[qt][np], 0, 0, 0);
            s2[qt][np] = __builtin_amdgcn_mfma_f32_16x16x32_bf16(kf2, aq2[qt][ks], s2[qt][np], 0, 0, 0);
          }
        }
      }
      // fixed-max softmax: p = exp2(s*SL + ma); accumulate per-lane partial l
      float ma[2][4];
#pragma unroll
      for (int np = 0; np < 2; np++)
#pragma unroll
        for (int r = 0; r < 4; r++)
          ma[np][r] = fmaf(((const float*)&mq[half * 2 + np])[r], ML, -ML);
#pragma unroll
      for (int qt = 0; qt < 2; qt++)
#pragma unroll
        for (int np = 0; np < 2; np++) {
#pragma unroll
          for (int r = 0; r < 4; r++) {
            float p1 = exp2f(fmaf(s1[qt][np][r], SL, ma[np][r]));
            float p2 = exp2f(fmaf(s2[qt][np][r], SL, ma[np][r]));
            lp1[qt] += p1; lp2[qt] += p2;
            s1[qt][np][r] = p1; s2[qt][np][r] = p2;
          }
          // write slot s4 = k'>>2 = np*4+quad, physical pos (s4 ^ (l15&7))*4:
          // bank-pair = 8*(l15&1) + (s4^x) is injective -> optimal 4-way for b64
          const int addr = l15 * 32 + (((np * 4 + quad) ^ sw) << 2);
          uint2 w1, w2;
          w1.x = pack2bf_rn(s1[qt][np][0], s1[qt][np][1]);
          w1.y = pack2bf_rn(s1[qt][np][2], s1[qt][np][3]);
          w2.x = pack2bf_rn(s2[qt][np][0], s2[qt][np][1]);
          w2.y = pack2bf_rn(s2[qt][np][2], s2[qt][np][3]);
          *(uint2*)&pw[(qt * 2 + 0) * 512 + addr] = w1;
          *(uint2*)&pw[(qt * 2 + 1) * 512 + addr] = w2;
        }
      asm volatile("s_waitcnt lgkmcnt(0)" ::: "memory");
      // PV for this k-half: O^T += V^T . P^T  (V frag shared by 2qt x 2streams)
      bf16x8 f1[2], f2[2];
      {
        const int ra = l15 * 32 + (((quad * 2 + 0) ^ sw) << 2);
        const int rb = l15 * 32 + (((quad * 2 + 1) ^ sw) << 2);
#pragma unroll
        for (int qt = 0; qt < 2; qt++) {
          union { bf16x8 v; uint2 u2[2]; } g1, g2;
          g1.u2[0] = *(const uint2*)&pw[(qt * 2 + 0) * 512 + ra];
          g1.u2[1] = *(const uint2*)&pw[(qt * 2 + 0) * 512 + rb];
          g2.u2[0] = *(const uint2*)&pw[(qt * 2 + 1) * 512 + ra];
          g2.u2[1] = *(const uint2*)&pw[(qt * 2 + 1) * 512 + rb];
          f1[qt] = g1.v; f2[qt] = g2.v;
        }
      }
#pragma unroll
      for (int dn = 0; dn < 8; dn++) {
        const int pp = ((half * 4 + quad) ^ sw) * 8;
        bf16x8 vf = *(const bf16x8*)&vts[cb * 8192 + (dn * 16 + l15) * 64 + pp];
#pragma unroll
        for (int qt = 0; qt < 2; qt++) {
          o1[qt][dn] = __builtin_amdgcn_mfma_f32_16x16x32_bf16(vf, f1[qt], o1[qt][dn], 0, 0, 0);
          o2[qt][dn] = __builtin_amdgcn_mfma_f32_16x16x32_bf16(vf, f2[qt], o2[qt][dn], 0, 0, 0);
        }
      }
      asm volatile("s_waitcnt lgkmcnt(0)" ::: "memory");  // pls reused next half
    }
  }
  // epilogue: reduce l across quads, out = O1/l1 - lam*O2/l2
  float lam = lamp[0];
#pragma unroll
  for (int qt = 0; qt < 2; qt++) {
    float l1 = lp1[qt], l2 = lp2[qt];
    l1 += __shfl_xor(l1, 16, 64); l1 += __shfl_xor(l1, 32, 64);
    l2 += __shfl_xor(l2, 16, 64); l2 += __shfl_xor(l2, 32, 64);
    float i1 = 1.f / l1, i2 = lam / l2;
    unsigned short* orow =
        out + (rowq + wave * 32 + qt * 16 + l15) * 2048 + h * 128 + quad * 4;
#pragma unroll
    for (int dn = 0; dn < 8; dn++) {
      uint2 st;
      st.x = pack2bf_rn(o1[qt][dn][0] * i1 - o2[qt][dn][0] * i2,
                        o1[qt][dn][1] * i1 - o2[qt][dn][1] * i2);
      st.y = pack2bf_rn(o1[qt][dn][2] * i1 - o2[qt][dn][2] * i2,
                        o1[qt][dn][3] * i1 - o2[qt][dn][3] * i2);
      *(uint2*)(orow + dn * 16) = st;
    }
  }
}

extern "C" void kernel_launch(void* const* d_in, const int* in_sizes, int n_in,
                              void* d_out, int out_size, void* d_ws, size_t ws_size,
                              hipStream_t stream) {
  (void)in_sizes; (void)n_in; (void)out_size; (void)ws_size;
  const float* hs   = (const float*)d_in[0];
  const float* mask = (const float*)d_in[1];
  const float* Wa   = (const float*)d_in[2];
  const float* ba   = (const float*)d_in[3];
  const float* Wp   = (const float*)d_in[4];
  const float* bp   = (const float*)d_in[5];
  const float* lam  = (const float*)d_in[6];
  float* out = (float*)d_out;
  unsigned short* ws = (unsigned short*)d_ws;

  // workspace (bf16 elems): 48Mi elems = 96 MiB
  unsigned short* hsb = ws;                                  // [4096][2048] (aliased by att)
  unsigned short* WtA = hsb + (long)4096 * 2048;             // [6144][2048]
  unsigned short* WtP = WtA + (long)6144 * 2048;             // [2048][2048]
  unsigned short* qQ  = WtP + (long)2048 * 2048;             // [4096][2048]
  unsigned short* K1p = qQ + (long)4096 * 2048;              // 2*16*32 tiles * 4096
  unsigned short* K2p = K1p + (long)2 * 16 * 2048 * 64;
  unsigned short* Vp  = K2p + (long)2 * 16 * 2048 * 64;      // 2*16*32 tiles * 8192
  unsigned short* att = hsb;                                 // alias (hsb dead after step 2)

  // 1) casts / weight transposes
  cvt_bf16_k<<<4096, 256, 0, stream>>>(hs, hsb, (long)4096 * 2048);
  cvt_transpose_k<<<dim3(192, 64), 256, 0, stream>>>(Wa, WtA, 6144, 2048);
  cvt_transpose_k<<<dim3(64, 64), 256, 0, stream>>>(Wp, WtP, 2048, 2048);
  // 2) qkv GEMM with fused Q/K-pack/V-pack epilogue
  gemm_qkv<<<dim3(48, 32), 256, 0, stream>>>(hsb, WtA, ba, qQ, K1p, K2p, Vp);
  // 3) differential flash attention (q-tile 128)
  attn_k<<<dim3(16, 16, 2), 256, 0, stream>>>(qQ, K1p, K2p, Vp, mask, lam, att);
  // 4) out = att @ W_proj + b_proj (f32 out)
  gemm_bt_f32<<<dim3(16, 32), 256, 0, stream>>>(att, WtP, bp, out, 2048, 2048);
}